// Round 11
// baseline (184.432 us; speedup 1.0000x reference)
//
#include <hip/hip_runtime.h>

#define NFEAT 128
#define HEADS 8
#define NHID 16
#define SLOPE 0.2f
#define BSH 8            // 256 dst nodes per bucket; NBUCK = ceil(N/256) <= 256 (N <= 65536)

typedef __fp16 f16x8 __attribute__((ext_vector_type(8)));   // MFMA A/B frag (4 VGPRs)
typedef __fp16 f16x2 __attribute__((ext_vector_type(2)));
typedef float  f4v   __attribute__((ext_vector_type(4)));   // MFMA C/D frag

__device__ __forceinline__ unsigned pack2h(float a, float b) {
    union { f16x2 h; unsigned u; } r;
    r.h = __builtin_amdgcn_cvt_pkrtz(a, b);
    return r.u;
}
__device__ __forceinline__ f16x2 as_f16x2(unsigned u) {
    union { unsigned u; f16x2 h; } r; r.u = u; return r.h;
}
// build an 8-element fp16 A/B fragment from 8 consecutive f32
__device__ __forceinline__ f16x8 frag_from_f32(const float* p) {
    float4 q0 = *(const float4*)p;
    float4 q1 = *(const float4*)(p + 4);
    union { f16x8 v; f16x2 h[4]; } r;
    r.h[0] = __builtin_amdgcn_cvt_pkrtz(q0.x, q0.y);
    r.h[1] = __builtin_amdgcn_cvt_pkrtz(q0.z, q0.w);
    r.h[2] = __builtin_amdgcn_cvt_pkrtz(q1.x, q1.y);
    r.h[3] = __builtin_amdgcn_cvt_pkrtz(q1.z, q1.w);
    return r.v;
}

// ---------------- bucketed CSR build ----------------

__global__ void k_zero(int* __restrict__ p, int m) {
    int i = blockIdx.x * blockDim.x + threadIdx.x;
    if (i < m) p[i] = 0;
}

__global__ __launch_bounds__(256) void k_bhist(const int* __restrict__ dst, int E,
                                               int* __restrict__ bcount) {
    __shared__ int h[256];
    int t = threadIdx.x;
    h[t] = 0;
    __syncthreads();
    int stride = gridDim.x * 256;
    for (int i = blockIdx.x * 256 + t; i < E; i += stride)
        atomicAdd(&h[dst[i] >> BSH], 1);
    __syncthreads();
    int v = h[t];
    if (v) atomicAdd(&bcount[t], v);
}

__global__ __launch_bounds__(256) void k_bscan(const int* __restrict__ bcount,
                                               int* __restrict__ pair_start,
                                               int* __restrict__ pair_cursor,
                                               int* __restrict__ row_start,
                                               int E, int n) {
    __shared__ int sh[256];
    int t = threadIdx.x;
    int nb = (n + 255) >> BSH;
    int v = (t < nb) ? bcount[t] : 0;
    sh[t] = v;
    __syncthreads();
    for (int off = 1; off < 256; off <<= 1) {
        int u = (t >= off) ? sh[t - off] : 0;
        __syncthreads();
        sh[t] += u;
        __syncthreads();
    }
    int excl = sh[t] - v;
    pair_start[t] = excl;
    pair_cursor[t] = excl;
    if (t == 0) row_start[n] = E + n;
}

__global__ __launch_bounds__(256) void k_bscatter(const int* __restrict__ src,
                                                  const int* __restrict__ dst,
                                                  int E, int chunk,
                                                  int* __restrict__ pair_cursor,
                                                  uint2* __restrict__ pairs) {
    __shared__ int cnt[256], base[256];
    int t = threadIdx.x;
    int beg = blockIdx.x * chunk;
    int end = min(beg + chunk, E);
    if (beg >= end) return;
    cnt[t] = 0;
    __syncthreads();
    for (int i = beg + t; i < end; i += 256)
        atomicAdd(&cnt[dst[i] >> BSH], 1);
    __syncthreads();
    int c = cnt[t];
    base[t] = c ? atomicAdd(&pair_cursor[t], c) : 0;
    __syncthreads();
    cnt[t] = 0;
    __syncthreads();
    for (int i = beg + t; i < end; i += 256) {
        int d = dst[i];
        int b = d >> BSH;
        int ofs = atomicAdd(&cnt[b], 1);
        pairs[base[b] + ofs] = make_uint2((unsigned)src[i], (unsigned)d);
    }
}

__global__ __launch_bounds__(256) void k_bucket_csr(const uint2* __restrict__ pairs,
                                                    const int* __restrict__ pair_start,
                                                    const int* __restrict__ bcount,
                                                    int* __restrict__ row_start,
                                                    int* __restrict__ csr, int n) {
    __shared__ int deg[256], sc[256];
    int b = blockIdx.x, t = threadIdx.x;
    int d0 = b << BSH;
    int nd = min(256, n - d0);
    deg[t] = (t < nd) ? 1 : 0;   // self loop
    __syncthreads();
    int pbeg = pair_start[b], pend = pbeg + bcount[b];
    for (int i = pbeg + t; i < pend; i += 256)
        atomicAdd(&deg[pairs[i].y - d0], 1);
    __syncthreads();
    int v = deg[t];
    sc[t] = v;
    __syncthreads();
    for (int off = 1; off < 256; off <<= 1) {
        int u = (t >= off) ? sc[t - off] : 0;
        __syncthreads();
        sc[t] += u;
        __syncthreads();
    }
    int excl = sc[t] - v;
    int cbase = pair_start[b] + d0;        // csr base of this bucket
    if (t < nd) row_start[d0 + t] = cbase + excl;
    __syncthreads();
    deg[t] = excl;                          // reuse as cursor
    __syncthreads();
    if (t < nd) {                           // self loop entry
        int pos = atomicAdd(&deg[t], 1);
        csr[cbase + pos] = d0 + t;
    }
    for (int i = pbeg + t; i < pend; i += 256) {
        uint2 p = pairs[i];
        int pos = atomicAdd(&deg[p.y - d0], 1);
        csr[cbase + pos] = (int)p.x;
    }
}

// ---------------- weight prep: Wt1[128c][128k] f16, Aat1[16][128] f16, W2t[16c][128k] f16 ----------------

__global__ __launch_bounds__(256) void k_prep(const float* __restrict__ W1,
                                              const float* __restrict__ as1,
                                              const float* __restrict__ ad1,
                                              const float* __restrict__ W2,
                                              unsigned* __restrict__ Wt1,      // [128][64] u32 (f16x2)
                                              __fp16* __restrict__ Aat1,       // [16][128]
                                              unsigned* __restrict__ W2t) {    // [16][64] u32 (f16x2)
    int t = blockIdx.x * 256 + threadIdx.x;
    if (t < 8192) {
        int c = t >> 6, m = t & 63;
        int k = 2 * m;
        Wt1[t] = pack2h(W1[k * 128 + c], W1[(k + 1) * 128 + c]);
    } else if (t < 10240) {
        int idx = t - 8192;
        int j = idx >> 7, k = idx & 127;
        float v = 0.f;
        if (j < 8)  { if ((k >> 4) == j)     v = as1[k]; }
        else        { if ((k >> 4) == j - 8) v = ad1[k]; }
        Aat1[idx] = (__fp16)v;
    } else if (t < 11264) {
        int idx = t - 10240;
        int c = idx >> 6, m = idx & 63;
        int k = 2 * m;
        W2t[idx] = pack2h(W2[k * 16 + c], W2[(k + 1) * 16 + c]);
    }
}

// ---------------- Layer 1 GEMM via MFMA (f16): h1 (group-major) = x @ W1, logits via 2nd MFMA ----------------
// h1s layout: [8 groups][n][8 u32]  (group g holds channels 16g..16g+15 = head g, f16x2 words)
// als_s layout: [8 groups][n] f32   (logit of head g)

__global__ __launch_bounds__(256) void k_gemm1m(const float* __restrict__ xf,
                                                const __fp16* __restrict__ Wt,
                                                const __fp16* __restrict__ Aat,
                                                unsigned* __restrict__ h1s,
                                                float* __restrict__ als_s,
                                                float* __restrict__ ald, int n) {
    __shared__ unsigned hl[4][32 * 64];   // per-wave h repack (swizzled), 32 KB
    int tid = threadIdx.x;
    int w = tid >> 6, l = tid & 63;
    int l15 = l & 15, lq = l >> 4;
    int wbase = blockIdx.x * 128 + w * 32;
    size_t slice = (size_t)n * 8;
    f4v acc[2][8] = {};
    int r0 = min(wbase + l15, n - 1);
    int r1 = min(wbase + 16 + l15, n - 1);
#pragma unroll
    for (int kb = 0; kb < 4; ++kb) {
        int ko = kb * 32 + lq * 8;
        f16x8 a0 = frag_from_f32(&xf[(size_t)r0 * 128 + ko]);
        f16x8 a1 = frag_from_f32(&xf[(size_t)r1 * 128 + ko]);
#pragma unroll
        for (int cg = 0; cg < 8; ++cg) {
            f16x8 b = *(const f16x8*)&Wt[(size_t)(cg * 16 + l15) * 128 + ko];
            acc[0][cg] = __builtin_amdgcn_mfma_f32_16x16x32_f16(a0, b, acc[0][cg], 0, 0, 0);
            acc[1][cg] = __builtin_amdgcn_mfma_f32_16x16x32_f16(a1, b, acc[1][cg], 0, 0, 0);
        }
    }
    unsigned* myl = hl[w];
#pragma unroll
    for (int T = 0; T < 2; ++T) {
#pragma unroll
        for (int cg = 0; cg < 8; ++cg) {
#pragma unroll
            for (int j = 0; j < 4; ++j) {
                float v = acc[T][cg][j];
                float vo = __shfl_xor(v, 1);
                if ((l15 & 1) == 0) {
                    int nd = T * 16 + lq * 4 + j;
                    int wd = cg * 8 + (l15 >> 1);
                    int widx = nd * 64 + (((wd >> 2) ^ (nd & 15)) << 2) + (wd & 3);
                    myl[widx] = pack2h(v, vo);
                }
            }
        }
    }
    __syncthreads();
    // group-major h1 store: granule l15 = words l15*4..l15*4+3 = channels 8*l15..8*l15+7 (group l15>>1)
#pragma unroll
    for (int it = 0; it < 8; ++it) {
        int nd = it * 4 + lq;
        int node = wbase + nd;
        uint4 vv = *(const uint4*)&myl[nd * 64 + ((l15 ^ (nd & 15)) << 2)];
        if (node < n)
            *(uint4*)&h1s[(size_t)(l15 >> 1) * slice + (size_t)node * 8 + (l15 & 1) * 4] = vv;
    }
    // attention logits: D2 = h_tile @ Aat^T  (16x16, K=128); col l15<8 = als head l15, col 8+hd = ald head hd
#pragma unroll
    for (int T = 0; T < 2; ++T) {
        f4v acca = {};
#pragma unroll
        for (int kb = 0; kb < 4; ++kb) {
            int nd = T * 16 + l15;
            f16x8 ah = *(const f16x8*)&myl[nd * 64 + (((kb * 4 + lq) ^ (nd & 15)) << 2)];
            f16x8 bb = *(const f16x8*)&Aat[l15 * 128 + kb * 32 + lq * 8];
            acca = __builtin_amdgcn_mfma_f32_16x16x32_f16(ah, bb, acca, 0, 0, 0);
        }
#pragma unroll
        for (int j = 0; j < 4; ++j) {
            int node = wbase + T * 16 + lq * 4 + j;
            if (node < n) {
                if (l15 < 8) als_s[(size_t)l15 * n + node] = acca[j];
                else         ald[(size_t)node * 8 + (l15 - 8)] = acca[j];
            }
        }
    }
}

// ---------------- Layer 1 aggregation (channel-split, XCD-affine) ----------------
// group g = blockIdx.x & 7 (lands on XCD g under round-robin dispatch); group g = head g.
// block = 256 thr = 4 waves; wave = 2 nodes x 4 edge-groups x 8 lanes; lane = 2 channels (1 u32).

__global__ __launch_bounds__(256) void k_agg1(const unsigned* __restrict__ h1s,
                                              const float* __restrict__ als_s,
                                              const float* __restrict__ ald,
                                              const float* __restrict__ bias,
                                              const int* __restrict__ row_start,
                                              const int* __restrict__ csr,
                                              unsigned* __restrict__ out1s, int n) {
    int t = threadIdx.x;
    int l = t & 63;
    int sub = l & 7;           // channel pair within group
    int eg = (l >> 3) & 3;     // edge group
    int g = blockIdx.x & 7;    // channel group == head
    int nn = (blockIdx.x >> 3) * 8 + (t >> 6) * 2 + (l >> 5);
    if (nn >= n) return;       // 32 lanes of a node exit together
    size_t slice = (size_t)n * 8;
    const unsigned* hg = h1s + (size_t)g * slice;
    const float* ag = als_s + (size_t)g * n;
    float aldv = ald[(size_t)nn * 8 + g];
    int beg = row_start[nn], end = row_start[nn + 1];
    int len = end - beg;
    int g0 = beg + ((len * eg) >> 2);
    int g1 = beg + ((len * (eg + 1)) >> 2);
    float a0 = 0.f, a1 = 0.f, dn = 0.f;
    f16x2 one2; one2[0] = (__fp16)1.f; one2[1] = (__fp16)1.f;
    int i = g0;
    for (; i + 2 <= g1; i += 2) {
        int s0 = csr[i];
        int s1 = csr[i + 1];
        float e0 = ag[s0] + aldv;
        float e1 = ag[s1] + aldv;
        unsigned v0 = hg[(size_t)s0 * 8 + sub];
        unsigned v1 = hg[(size_t)s1 * 8 + sub];
        e0 = (e0 < 0.f) ? SLOPE * e0 : e0;
        e1 = (e1 < 0.f) ? SLOPE * e1 : e1;
        f16x2 xx = __builtin_amdgcn_cvt_pkrtz(__expf(e0), __expf(e1));
        dn = __builtin_amdgcn_fdot2(xx, one2, dn, false);
        unsigned lo = __builtin_amdgcn_perm(v1, v0, 0x05040100u);
        unsigned hi = __builtin_amdgcn_perm(v1, v0, 0x07060302u);
        a0 = __builtin_amdgcn_fdot2(xx, as_f16x2(lo), a0, false);
        a1 = __builtin_amdgcn_fdot2(xx, as_f16x2(hi), a1, false);
    }
    if (i < g1) {
        int s0 = csr[i];
        float e0 = ag[s0] + aldv;
        unsigned v0 = hg[(size_t)s0 * 8 + sub];
        e0 = (e0 < 0.f) ? SLOPE * e0 : e0;
        float x0 = __expf(e0);
        dn += x0;
        f16x2 p = as_f16x2(v0);
        a0 = fmaf(x0, (float)p[0], a0);
        a1 = fmaf(x0, (float)p[1], a1);
    }
    a0 += __shfl_xor(a0, 8); a0 += __shfl_xor(a0, 16);
    a1 += __shfl_xor(a1, 8); a1 += __shfl_xor(a1, 16);
    dn += __shfl_xor(dn, 8); dn += __shfl_xor(dn, 16);
    if (eg == 0) {
        float inv = 1.f / dn;
        int ch = g * 16 + sub * 2;
        float r0 = fmaxf(a0 * inv + bias[ch], 0.f);
        float r1 = fmaxf(a1 * inv + bias[ch + 1], 0.f);
        out1s[(size_t)g * slice + (size_t)nn * 8 + sub] = pack2h(r0, r1);
    }
}

// ---------------- Layer 2 GEMM via MFMA (f16); A from group-major out1s ----------------

__global__ __launch_bounds__(256) void k_gemm2m(const unsigned* __restrict__ o1s,
                                                const __fp16* __restrict__ W2t,
                                                const float* __restrict__ as2,
                                                const float* __restrict__ ad2,
                                                __fp16* __restrict__ h2,
                                                float* __restrict__ als,
                                                float* __restrict__ ald, int n) {
    int tid = threadIdx.x;
    int w = tid >> 6, l = tid & 63;
    int l15 = l & 15, lq = l >> 4;
    int wbase = blockIdx.x * 128 + w * 32;
    size_t slice = (size_t)n * 8;
    f4v acc[2] = {};
    int r0 = min(wbase + l15, n - 1);
    int r1 = min(wbase + 16 + l15, n - 1);
#pragma unroll
    for (int kb = 0; kb < 4; ++kb) {
        int ko = kb * 32 + lq * 8;                 // 8 consecutive channels, one group
        size_t goff = (size_t)(ko >> 4) * slice + ((ko & 15) >> 1);
        f16x8 a0 = *(const f16x8*)&o1s[goff + (size_t)r0 * 8];
        f16x8 a1 = *(const f16x8*)&o1s[goff + (size_t)r1 * 8];
        f16x8 b  = *(const f16x8*)&W2t[(size_t)l15 * 128 + ko];
        acc[0] = __builtin_amdgcn_mfma_f32_16x16x32_f16(a0, b, acc[0], 0, 0, 0);
        acc[1] = __builtin_amdgcn_mfma_f32_16x16x32_f16(a1, b, acc[1], 0, 0, 0);
    }
    float asv = as2[l15], adv = ad2[l15];
#pragma unroll
    for (int T = 0; T < 2; ++T) {
#pragma unroll
        for (int j = 0; j < 4; ++j) {
            int node = wbase + T * 16 + lq * 4 + j;
            float hv = acc[T][j];
            float ps = hv * asv, pd = hv * adv;
            ps += __shfl_xor(ps, 1); ps += __shfl_xor(ps, 2);
            ps += __shfl_xor(ps, 4); ps += __shfl_xor(ps, 8);
            pd += __shfl_xor(pd, 1); pd += __shfl_xor(pd, 2);
            pd += __shfl_xor(pd, 4); pd += __shfl_xor(pd, 8);
            if (node < n) {
                h2[(size_t)node * 16 + l15] = (__fp16)hv;
                if (l15 == 0) { als[node] = ps; ald[node] = pd; }
            }
        }
    }
}

// ---------------- Layer 2 aggregation ----------------
// 1 wave per node; 4 edge-groups of 16 lanes; lane lc owns 1 channel (f16 2B of the 32B row).

__global__ __launch_bounds__(256) void k_agg2(const __fp16* __restrict__ h,
                                              const float* __restrict__ als,
                                              const float* __restrict__ ald,
                                              const float* __restrict__ bias,
                                              const int* __restrict__ row_start,
                                              const int* __restrict__ csr_src,
                                              float* __restrict__ out, int n) {
    int t = threadIdx.x;
    int l = t & 63;
    int lc = l & 15, eg = l >> 4;
    int nn = blockIdx.x * 4 + (t >> 6);
    if (nn >= n) return;
    int beg = row_start[nn], end = row_start[nn + 1];
    int len = end - beg;
    int g0 = beg + ((len * eg) >> 2);
    int g1 = beg + ((len * (eg + 1)) >> 2);
    float aldv = ald[nn];
    float ac0 = 0.f, ac1 = 0.f, dn0 = 0.f, dn1 = 0.f;
    int i = g0;
    for (; i + 2 <= g1; i += 2) {
        int s0 = csr_src[i], s1 = csr_src[i + 1];
        float e0 = als[s0], e1 = als[s1];
        float v0 = (float)h[(size_t)s0 * 16 + lc];
        float v1 = (float)h[(size_t)s1 * 16 + lc];
        e0 += aldv; e0 = (e0 < 0.f) ? SLOPE * e0 : e0;
        e1 += aldv; e1 = (e1 < 0.f) ? SLOPE * e1 : e1;
        float x0 = __expf(e0), x1 = __expf(e1);
        dn0 += x0; dn1 += x1;
        ac0 = fmaf(x0, v0, ac0);
        ac1 = fmaf(x1, v1, ac1);
    }
    if (i < g1) {
        int s0 = csr_src[i];
        float e0 = als[s0] + aldv;
        e0 = (e0 < 0.f) ? SLOPE * e0 : e0;
        float x0 = __expf(e0);
        dn0 += x0;
        ac0 = fmaf(x0, (float)h[(size_t)s0 * 16 + lc], ac0);
    }
    float ac = ac0 + ac1, dn = dn0 + dn1;
    ac += __shfl_xor(ac, 16); ac += __shfl_xor(ac, 32);
    dn += __shfl_xor(dn, 16); dn += __shfl_xor(dn, 32);
    if (eg == 0) out[(size_t)nn * 16 + lc] = fmaxf(ac / dn + bias[lc], 0.f);
}

// ---------------- launch ----------------

extern "C" void kernel_launch(void* const* d_in, const int* in_sizes, int n_in,
                              void* d_out, int out_size, void* d_ws, size_t ws_size,
                              hipStream_t stream) {
    const float* x   = (const float*)d_in[0];
    const int*   ei  = (const int*)d_in[1];
    const float* W1  = (const float*)d_in[2];
    const float* as1 = (const float*)d_in[3];
    const float* ad1 = (const float*)d_in[4];
    const float* b1  = (const float*)d_in[5];
    const float* W2  = (const float*)d_in[6];
    const float* as2 = (const float*)d_in[7];
    const float* ad2 = (const float*)d_in[8];
    const float* b2  = (const float*)d_in[9];

    int N = in_sizes[0] / NFEAT;
    int E = in_sizes[1] / 2;
    const int* srcp = ei;
    const int* dstp = ei + E;
    int NBUCK = (N + 255) >> BSH;

    char* ws = (char*)d_ws;
    size_t off = 0;
    auto take = [&](size_t bytes) -> char* {
        char* p = ws + off;
        off = (off + bytes + 255) & ~(size_t)255;
        return p;
    };
    int*       row_start = (int*)take((size_t)(N + 1) * 4);
    int*       bcount    = (int*)take(256 * 4);
    int*       pstart    = (int*)take(256 * 4);
    int*       pcursor   = (int*)take(256 * 4);
    uint2*     pairs     = (uint2*)take((size_t)E * 8);
    int*       csr       = (int*)take((size_t)(E + N) * 4);
    unsigned*  Wt1       = (unsigned*)take((size_t)128 * 64 * 4);
    __fp16*    Aat1      = (__fp16*)take((size_t)16 * 128 * 2);
    unsigned*  W2t       = (unsigned*)take((size_t)16 * 64 * 4);
    unsigned*  h1s       = (unsigned*)take((size_t)N * 64 * 4);   // [8][N][8] u32
    float*     als_s     = (float*)take((size_t)N * 8 * 4);       // [8][N] f32
    float*     ald1      = (float*)take((size_t)N * 8 * 4);
    unsigned*  out1s     = (unsigned*)take((size_t)N * 64 * 4);   // [8][N][8] u32
    __fp16*    h2        = (__fp16*)take((size_t)N * 16 * 2);
    float*     als2      = (float*)take((size_t)N * 4);
    float*     ald2      = (float*)take((size_t)N * 4);

    // CSR build (bucketed counting sort)
    k_zero<<<1, 256, 0, stream>>>(bcount, 256);
    k_bhist<<<256, 256, 0, stream>>>(dstp, E, bcount);
    k_bscan<<<1, 256, 0, stream>>>(bcount, pstart, pcursor, row_start, E, N);
    int chunk = (E + 127) / 128;
    k_bscatter<<<128, 256, 0, stream>>>(srcp, dstp, E, chunk, pcursor, pairs);
    k_bucket_csr<<<NBUCK, 256, 0, stream>>>(pairs, pstart, bcount, row_start, csr, N);

    // layers
    k_prep<<<44, 256, 0, stream>>>(W1, as1, ad1, W2, Wt1, Aat1, W2t);
    k_gemm1m<<<(N + 127) / 128, 256, 0, stream>>>(x, (const __fp16*)Wt1, Aat1,
                                                  h1s, als_s, ald1, N);
    int nb1 = ((N + 7) / 8) * 8;   // 8 nodes per block x 8 channel groups
    k_agg1<<<nb1, 256, 0, stream>>>(h1s, als_s, ald1, b1, row_start, csr, out1s, N);
    k_gemm2m<<<(N + 127) / 128, 256, 0, stream>>>(out1s, (const __fp16*)W2t,
                                                  as2, ad2, h2, als2, ald2, N);
    k_agg2<<<(N + 3) / 4, 256, 0, stream>>>(h2, als2, ald2, b2, row_start, csr, (float*)d_out, N);
}

// Round 12
// 184.309 us; speedup vs baseline: 1.0007x; 1.0007x over previous
//
#include <hip/hip_runtime.h>

#define NFEAT 128
#define HEADS 8
#define NHID 16
#define SLOPE 0.2f
#define BSH 8            // 256 dst nodes per bucket; NBUCK = ceil(N/256) <= 256 (N <= 65536)

typedef __fp16 f16x8 __attribute__((ext_vector_type(8)));   // MFMA A/B frag (4 VGPRs)
typedef __fp16 f16x2 __attribute__((ext_vector_type(2)));
typedef float  f4v   __attribute__((ext_vector_type(4)));   // MFMA C/D frag

__device__ __forceinline__ unsigned pack2h(float a, float b) {
    union { f16x2 h; unsigned u; } r;
    r.h = __builtin_amdgcn_cvt_pkrtz(a, b);
    return r.u;
}
__device__ __forceinline__ f16x2 as_f16x2(unsigned u) {
    union { unsigned u; f16x2 h; } r; r.u = u; return r.h;
}
// build an 8-element fp16 A/B fragment from 8 consecutive f32
__device__ __forceinline__ f16x8 frag_from_f32(const float* p) {
    float4 q0 = *(const float4*)p;
    float4 q1 = *(const float4*)(p + 4);
    union { f16x8 v; f16x2 h[4]; } r;
    r.h[0] = __builtin_amdgcn_cvt_pkrtz(q0.x, q0.y);
    r.h[1] = __builtin_amdgcn_cvt_pkrtz(q0.z, q0.w);
    r.h[2] = __builtin_amdgcn_cvt_pkrtz(q1.x, q1.y);
    r.h[3] = __builtin_amdgcn_cvt_pkrtz(q1.z, q1.w);
    return r.v;
}

// ---------------- bucketed CSR build ----------------

__global__ void k_zero(int* __restrict__ p, int m) {
    int i = blockIdx.x * blockDim.x + threadIdx.x;
    if (i < m) p[i] = 0;
}

__global__ __launch_bounds__(256) void k_bhist(const int* __restrict__ dst, int E,
                                               int* __restrict__ bcount) {
    __shared__ int h[256];
    int t = threadIdx.x;
    h[t] = 0;
    __syncthreads();
    int stride = gridDim.x * 256;
    for (int i = blockIdx.x * 256 + t; i < E; i += stride)
        atomicAdd(&h[dst[i] >> BSH], 1);
    __syncthreads();
    int v = h[t];
    if (v) atomicAdd(&bcount[t], v);
}

__global__ __launch_bounds__(256) void k_bscan(const int* __restrict__ bcount,
                                               int* __restrict__ pair_start,
                                               int* __restrict__ pair_cursor,
                                               int* __restrict__ row_start,
                                               int E, int n) {
    __shared__ int sh[256];
    int t = threadIdx.x;
    int nb = (n + 255) >> BSH;
    int v = (t < nb) ? bcount[t] : 0;
    sh[t] = v;
    __syncthreads();
    for (int off = 1; off < 256; off <<= 1) {
        int u = (t >= off) ? sh[t - off] : 0;
        __syncthreads();
        sh[t] += u;
        __syncthreads();
    }
    int excl = sh[t] - v;
    pair_start[t] = excl;
    pair_cursor[t] = excl;
    if (t == 0) row_start[n] = E + n;
}

__global__ __launch_bounds__(256) void k_bscatter(const int* __restrict__ src,
                                                  const int* __restrict__ dst,
                                                  int E, int chunk,
                                                  int* __restrict__ pair_cursor,
                                                  uint2* __restrict__ pairs) {
    __shared__ int cnt[256], base[256];
    int t = threadIdx.x;
    int beg = blockIdx.x * chunk;
    int end = min(beg + chunk, E);
    if (beg >= end) return;
    cnt[t] = 0;
    __syncthreads();
    for (int i = beg + t; i < end; i += 256)
        atomicAdd(&cnt[dst[i] >> BSH], 1);
    __syncthreads();
    int c = cnt[t];
    base[t] = c ? atomicAdd(&pair_cursor[t], c) : 0;
    __syncthreads();
    cnt[t] = 0;
    __syncthreads();
    for (int i = beg + t; i < end; i += 256) {
        int d = dst[i];
        int b = d >> BSH;
        int ofs = atomicAdd(&cnt[b], 1);
        pairs[base[b] + ofs] = make_uint2((unsigned)src[i], (unsigned)d);
    }
}

__global__ __launch_bounds__(256) void k_bucket_csr(const uint2* __restrict__ pairs,
                                                    const int* __restrict__ pair_start,
                                                    const int* __restrict__ bcount,
                                                    int* __restrict__ row_start,
                                                    int* __restrict__ csr, int n) {
    __shared__ int deg[256], sc[256];
    int b = blockIdx.x, t = threadIdx.x;
    int d0 = b << BSH;
    int nd = min(256, n - d0);
    deg[t] = (t < nd) ? 1 : 0;   // self loop
    __syncthreads();
    int pbeg = pair_start[b], pend = pbeg + bcount[b];
    for (int i = pbeg + t; i < pend; i += 256)
        atomicAdd(&deg[pairs[i].y - d0], 1);
    __syncthreads();
    int v = deg[t];
    sc[t] = v;
    __syncthreads();
    for (int off = 1; off < 256; off <<= 1) {
        int u = (t >= off) ? sc[t - off] : 0;
        __syncthreads();
        sc[t] += u;
        __syncthreads();
    }
    int excl = sc[t] - v;
    int cbase = pair_start[b] + d0;        // csr base of this bucket
    if (t < nd) row_start[d0 + t] = cbase + excl;
    __syncthreads();
    deg[t] = excl;                          // reuse as cursor
    __syncthreads();
    if (t < nd) {                           // self loop entry
        int pos = atomicAdd(&deg[t], 1);
        csr[cbase + pos] = d0 + t;
    }
    for (int i = pbeg + t; i < pend; i += 256) {
        uint2 p = pairs[i];
        int pos = atomicAdd(&deg[p.y - d0], 1);
        csr[cbase + pos] = (int)p.x;
    }
}

// ---------------- weight prep: Wt1[128c][128k] f16, Aat1[16][128] f16, W2t[16c][128k] f16 ----------------

__global__ __launch_bounds__(256) void k_prep(const float* __restrict__ W1,
                                              const float* __restrict__ as1,
                                              const float* __restrict__ ad1,
                                              const float* __restrict__ W2,
                                              unsigned* __restrict__ Wt1,      // [128][64] u32 (f16x2)
                                              __fp16* __restrict__ Aat1,       // [16][128]
                                              unsigned* __restrict__ W2t) {    // [16][64] u32 (f16x2)
    int t = blockIdx.x * 256 + threadIdx.x;
    if (t < 8192) {
        int c = t >> 6, m = t & 63;
        int k = 2 * m;
        Wt1[t] = pack2h(W1[k * 128 + c], W1[(k + 1) * 128 + c]);
    } else if (t < 10240) {
        int idx = t - 8192;
        int j = idx >> 7, k = idx & 127;
        float v = 0.f;
        if (j < 8)  { if ((k >> 4) == j)     v = as1[k]; }
        else        { if ((k >> 4) == j - 8) v = ad1[k]; }
        Aat1[idx] = (__fp16)v;
    } else if (t < 11264) {
        int idx = t - 10240;
        int c = idx >> 6, m = idx & 63;
        int k = 2 * m;
        W2t[idx] = pack2h(W2[k * 16 + c], W2[(k + 1) * 16 + c]);
    }
}

// ---------------- Layer 1 GEMM via MFMA (f16): h1 (group-major) = x @ W1, logits via 2nd MFMA ----------------
// h1s layout: [8 groups][n][8 u32]  (group g holds channels 16g..16g+15 = head g, f16x2 words)
// als_s layout: [8 groups][n] f32   (logit of head g)

__global__ __launch_bounds__(256) void k_gemm1m(const float* __restrict__ xf,
                                                const __fp16* __restrict__ Wt,
                                                const __fp16* __restrict__ Aat,
                                                unsigned* __restrict__ h1s,
                                                float* __restrict__ als_s,
                                                float* __restrict__ ald, int n) {
    __shared__ unsigned hl[4][32 * 64];   // per-wave h repack (swizzled), 32 KB
    int tid = threadIdx.x;
    int w = tid >> 6, l = tid & 63;
    int l15 = l & 15, lq = l >> 4;
    int wbase = blockIdx.x * 128 + w * 32;
    size_t slice = (size_t)n * 8;
    f4v acc[2][8] = {};
    int r0 = min(wbase + l15, n - 1);
    int r1 = min(wbase + 16 + l15, n - 1);
#pragma unroll
    for (int kb = 0; kb < 4; ++kb) {
        int ko = kb * 32 + lq * 8;
        f16x8 a0 = frag_from_f32(&xf[(size_t)r0 * 128 + ko]);
        f16x8 a1 = frag_from_f32(&xf[(size_t)r1 * 128 + ko]);
#pragma unroll
        for (int cg = 0; cg < 8; ++cg) {
            f16x8 b = *(const f16x8*)&Wt[(size_t)(cg * 16 + l15) * 128 + ko];
            acc[0][cg] = __builtin_amdgcn_mfma_f32_16x16x32_f16(a0, b, acc[0][cg], 0, 0, 0);
            acc[1][cg] = __builtin_amdgcn_mfma_f32_16x16x32_f16(a1, b, acc[1][cg], 0, 0, 0);
        }
    }
    unsigned* myl = hl[w];
#pragma unroll
    for (int T = 0; T < 2; ++T) {
#pragma unroll
        for (int cg = 0; cg < 8; ++cg) {
#pragma unroll
            for (int j = 0; j < 4; ++j) {
                float v = acc[T][cg][j];
                float vo = __shfl_xor(v, 1);
                if ((l15 & 1) == 0) {
                    int nd = T * 16 + lq * 4 + j;
                    int wd = cg * 8 + (l15 >> 1);
                    int widx = nd * 64 + (((wd >> 2) ^ (nd & 15)) << 2) + (wd & 3);
                    myl[widx] = pack2h(v, vo);
                }
            }
        }
    }
    __syncthreads();
    // group-major h1 store: granule l15 = words l15*4..l15*4+3 = channels 8*l15..8*l15+7 (group l15>>1)
#pragma unroll
    for (int it = 0; it < 8; ++it) {
        int nd = it * 4 + lq;
        int node = wbase + nd;
        uint4 vv = *(const uint4*)&myl[nd * 64 + ((l15 ^ (nd & 15)) << 2)];
        if (node < n)
            *(uint4*)&h1s[(size_t)(l15 >> 1) * slice + (size_t)node * 8 + (l15 & 1) * 4] = vv;
    }
    // attention logits: D2 = h_tile @ Aat^T  (16x16, K=128); col l15<8 = als head l15, col 8+hd = ald head hd
#pragma unroll
    for (int T = 0; T < 2; ++T) {
        f4v acca = {};
#pragma unroll
        for (int kb = 0; kb < 4; ++kb) {
            int nd = T * 16 + l15;
            f16x8 ah = *(const f16x8*)&myl[nd * 64 + (((kb * 4 + lq) ^ (nd & 15)) << 2)];
            f16x8 bb = *(const f16x8*)&Aat[l15 * 128 + kb * 32 + lq * 8];
            acca = __builtin_amdgcn_mfma_f32_16x16x32_f16(ah, bb, acca, 0, 0, 0);
        }
#pragma unroll
        for (int j = 0; j < 4; ++j) {
            int node = wbase + T * 16 + lq * 4 + j;
            if (node < n) {
                if (l15 < 8) als_s[(size_t)l15 * n + node] = acca[j];
                else         ald[(size_t)node * 8 + (l15 - 8)] = acca[j];
            }
        }
    }
}

// ---------------- Layer 1 aggregation (channel-split, XCD-affine, 16B/lane) ----------------
// group g = blockIdx.x & 7 (XCD g under round-robin); 8 nodes per block.
// node gets 32 lanes = 16 edge-slots x 2 channel-lanes (uint4 = 16B = 8 channels each).
// Same total instruction count per edge as the non-split kernel (2 lanes x 8 groups = 16 lane-visits),
// but every h1s/als_s gather hits the local XCD L2.

__global__ __launch_bounds__(256) void k_agg1(const unsigned* __restrict__ h1s,
                                              const float* __restrict__ als_s,
                                              const float* __restrict__ ald,
                                              const float* __restrict__ bias,
                                              const int* __restrict__ row_start,
                                              const int* __restrict__ csr,
                                              unsigned* __restrict__ out1s, int n) {
    int t = threadIdx.x;
    int l = t & 63;
    int cl = l & 1;            // channel half (8 channels = 16B)
    int es = (l >> 1) & 15;    // edge slot
    int g = blockIdx.x & 7;    // channel group == head
    int nn = (blockIdx.x >> 3) * 8 + (t >> 6) * 2 + (l >> 5);
    if (nn >= n) return;       // 32 lanes of a node exit together
    size_t slice = (size_t)n * 8;
    const unsigned* hg = h1s + (size_t)g * slice + cl * 4;
    const float* ag = als_s + (size_t)g * n;
    float aldv = ald[(size_t)nn * 8 + g];
    int beg = row_start[nn], end = row_start[nn + 1];
    int len = end - beg;
    int g0 = beg + ((len * es) >> 4);
    int g1 = beg + ((len * (es + 1)) >> 4);
    float a[8] = {0.f, 0.f, 0.f, 0.f, 0.f, 0.f, 0.f, 0.f};
    float dn = 0.f;
    for (int i = g0; i < g1; ++i) {
        int s = csr[i];
        float e = ag[s] + aldv;
        uint4 v = *(const uint4*)&hg[(size_t)s * 8];
        e = (e < 0.f) ? SLOPE * e : e;
        float xv = __expf(e);
        dn += xv;
        f16x2 p0 = as_f16x2(v.x), p1 = as_f16x2(v.y);
        f16x2 p2 = as_f16x2(v.z), p3 = as_f16x2(v.w);
        a[0] = fmaf(xv, (float)p0[0], a[0]); a[1] = fmaf(xv, (float)p0[1], a[1]);
        a[2] = fmaf(xv, (float)p1[0], a[2]); a[3] = fmaf(xv, (float)p1[1], a[3]);
        a[4] = fmaf(xv, (float)p2[0], a[4]); a[5] = fmaf(xv, (float)p2[1], a[5]);
        a[6] = fmaf(xv, (float)p3[0], a[6]); a[7] = fmaf(xv, (float)p3[1], a[7]);
    }
    // reduce over the 16 edge-slots (lane strides 2,4,8,16 keep cl and node bits intact)
#pragma unroll
    for (int j = 0; j < 8; ++j) {
        a[j] += __shfl_xor(a[j], 2);
        a[j] += __shfl_xor(a[j], 4);
        a[j] += __shfl_xor(a[j], 8);
        a[j] += __shfl_xor(a[j], 16);
    }
    dn += __shfl_xor(dn, 2);
    dn += __shfl_xor(dn, 4);
    dn += __shfl_xor(dn, 8);
    dn += __shfl_xor(dn, 16);
    if (es == 0) {
        float inv = 1.f / dn;
        int ch = g * 16 + cl * 8;
        float4 b0 = *(const float4*)&bias[ch];
        float4 b1 = *(const float4*)&bias[ch + 4];
        uint4 o;
        o.x = pack2h(fmaxf(a[0] * inv + b0.x, 0.f), fmaxf(a[1] * inv + b0.y, 0.f));
        o.y = pack2h(fmaxf(a[2] * inv + b0.z, 0.f), fmaxf(a[3] * inv + b0.w, 0.f));
        o.z = pack2h(fmaxf(a[4] * inv + b1.x, 0.f), fmaxf(a[5] * inv + b1.y, 0.f));
        o.w = pack2h(fmaxf(a[6] * inv + b1.z, 0.f), fmaxf(a[7] * inv + b1.w, 0.f));
        *(uint4*)&out1s[(size_t)g * slice + (size_t)nn * 8 + cl * 4] = o;
    }
}

// ---------------- Layer 2 GEMM via MFMA (f16); A from group-major out1s ----------------

__global__ __launch_bounds__(256) void k_gemm2m(const unsigned* __restrict__ o1s,
                                                const __fp16* __restrict__ W2t,
                                                const float* __restrict__ as2,
                                                const float* __restrict__ ad2,
                                                __fp16* __restrict__ h2,
                                                float* __restrict__ als,
                                                float* __restrict__ ald, int n) {
    int tid = threadIdx.x;
    int w = tid >> 6, l = tid & 63;
    int l15 = l & 15, lq = l >> 4;
    int wbase = blockIdx.x * 128 + w * 32;
    size_t slice = (size_t)n * 8;
    f4v acc[2] = {};
    int r0 = min(wbase + l15, n - 1);
    int r1 = min(wbase + 16 + l15, n - 1);
#pragma unroll
    for (int kb = 0; kb < 4; ++kb) {
        int ko = kb * 32 + lq * 8;                 // 8 consecutive channels, one group
        size_t goff = (size_t)(ko >> 4) * slice + ((ko & 15) >> 1);
        f16x8 a0 = *(const f16x8*)&o1s[goff + (size_t)r0 * 8];
        f16x8 a1 = *(const f16x8*)&o1s[goff + (size_t)r1 * 8];
        f16x8 b  = *(const f16x8*)&W2t[(size_t)l15 * 128 + ko];
        acc[0] = __builtin_amdgcn_mfma_f32_16x16x32_f16(a0, b, acc[0], 0, 0, 0);
        acc[1] = __builtin_amdgcn_mfma_f32_16x16x32_f16(a1, b, acc[1], 0, 0, 0);
    }
    float asv = as2[l15], adv = ad2[l15];
#pragma unroll
    for (int T = 0; T < 2; ++T) {
#pragma unroll
        for (int j = 0; j < 4; ++j) {
            int node = wbase + T * 16 + lq * 4 + j;
            float hv = acc[T][j];
            float ps = hv * asv, pd = hv * adv;
            ps += __shfl_xor(ps, 1); ps += __shfl_xor(ps, 2);
            ps += __shfl_xor(ps, 4); ps += __shfl_xor(ps, 8);
            pd += __shfl_xor(pd, 1); pd += __shfl_xor(pd, 2);
            pd += __shfl_xor(pd, 4); pd += __shfl_xor(pd, 8);
            if (node < n) {
                h2[(size_t)node * 16 + l15] = (__fp16)hv;
                if (l15 == 0) { als[node] = ps; ald[node] = pd; }
            }
        }
    }
}

// ---------------- Layer 2 aggregation ----------------
// 1 wave per node; 4 edge-groups of 16 lanes; lane lc owns 1 channel (f16 2B of the 32B row).

__global__ __launch_bounds__(256) void k_agg2(const __fp16* __restrict__ h,
                                              const float* __restrict__ als,
                                              const float* __restrict__ ald,
                                              const float* __restrict__ bias,
                                              const int* __restrict__ row_start,
                                              const int* __restrict__ csr_src,
                                              float* __restrict__ out, int n) {
    int t = threadIdx.x;
    int l = t & 63;
    int lc = l & 15, eg = l >> 4;
    int nn = blockIdx.x * 4 + (t >> 6);
    if (nn >= n) return;
    int beg = row_start[nn], end = row_start[nn + 1];
    int len = end - beg;
    int g0 = beg + ((len * eg) >> 2);
    int g1 = beg + ((len * (eg + 1)) >> 2);
    float aldv = ald[nn];
    float ac0 = 0.f, ac1 = 0.f, dn0 = 0.f, dn1 = 0.f;
    int i = g0;
    for (; i + 2 <= g1; i += 2) {
        int s0 = csr_src[i], s1 = csr_src[i + 1];
        float e0 = als[s0], e1 = als[s1];
        float v0 = (float)h[(size_t)s0 * 16 + lc];
        float v1 = (float)h[(size_t)s1 * 16 + lc];
        e0 += aldv; e0 = (e0 < 0.f) ? SLOPE * e0 : e0;
        e1 += aldv; e1 = (e1 < 0.f) ? SLOPE * e1 : e1;
        float x0 = __expf(e0), x1 = __expf(e1);
        dn0 += x0; dn1 += x1;
        ac0 = fmaf(x0, v0, ac0);
        ac1 = fmaf(x1, v1, ac1);
    }
    if (i < g1) {
        int s0 = csr_src[i];
        float e0 = als[s0] + aldv;
        e0 = (e0 < 0.f) ? SLOPE * e0 : e0;
        float x0 = __expf(e0);
        dn0 += x0;
        ac0 = fmaf(x0, (float)h[(size_t)s0 * 16 + lc], ac0);
    }
    float ac = ac0 + ac1, dn = dn0 + dn1;
    ac += __shfl_xor(ac, 16); ac += __shfl_xor(ac, 32);
    dn += __shfl_xor(dn, 16); dn += __shfl_xor(dn, 32);
    if (eg == 0) out[(size_t)nn * 16 + lc] = fmaxf(ac / dn + bias[lc], 0.f);
}

// ---------------- launch ----------------

extern "C" void kernel_launch(void* const* d_in, const int* in_sizes, int n_in,
                              void* d_out, int out_size, void* d_ws, size_t ws_size,
                              hipStream_t stream) {
    const float* x   = (const float*)d_in[0];
    const int*   ei  = (const int*)d_in[1];
    const float* W1  = (const float*)d_in[2];
    const float* as1 = (const float*)d_in[3];
    const float* ad1 = (const float*)d_in[4];
    const float* b1  = (const float*)d_in[5];
    const float* W2  = (const float*)d_in[6];
    const float* as2 = (const float*)d_in[7];
    const float* ad2 = (const float*)d_in[8];
    const float* b2  = (const float*)d_in[9];

    int N = in_sizes[0] / NFEAT;
    int E = in_sizes[1] / 2;
    const int* srcp = ei;
    const int* dstp = ei + E;
    int NBUCK = (N + 255) >> BSH;

    char* ws = (char*)d_ws;
    size_t off = 0;
    auto take = [&](size_t bytes) -> char* {
        char* p = ws + off;
        off = (off + bytes + 255) & ~(size_t)255;
        return p;
    };
    int*       row_start = (int*)take((size_t)(N + 1) * 4);
    int*       bcount    = (int*)take(256 * 4);
    int*       pstart    = (int*)take(256 * 4);
    int*       pcursor   = (int*)take(256 * 4);
    uint2*     pairs     = (uint2*)take((size_t)E * 8);
    int*       csr       = (int*)take((size_t)(E + N) * 4);
    unsigned*  Wt1       = (unsigned*)take((size_t)128 * 64 * 4);
    __fp16*    Aat1      = (__fp16*)take((size_t)16 * 128 * 2);
    unsigned*  W2t       = (unsigned*)take((size_t)16 * 64 * 4);
    unsigned*  h1s       = (unsigned*)take((size_t)N * 64 * 4);   // [8][N][8] u32
    float*     als_s     = (float*)take((size_t)N * 8 * 4);       // [8][N] f32
    float*     ald1      = (float*)take((size_t)N * 8 * 4);
    unsigned*  out1s     = (unsigned*)take((size_t)N * 64 * 4);   // [8][N][8] u32
    __fp16*    h2        = (__fp16*)take((size_t)N * 16 * 2);
    float*     als2      = (float*)take((size_t)N * 4);
    float*     ald2      = (float*)take((size_t)N * 4);

    // CSR build (bucketed counting sort)
    k_zero<<<1, 256, 0, stream>>>(bcount, 256);
    k_bhist<<<256, 256, 0, stream>>>(dstp, E, bcount);
    k_bscan<<<1, 256, 0, stream>>>(bcount, pstart, pcursor, row_start, E, N);
    int chunk = (E + 127) / 128;
    k_bscatter<<<128, 256, 0, stream>>>(srcp, dstp, E, chunk, pcursor, pairs);
    k_bucket_csr<<<NBUCK, 256, 0, stream>>>(pairs, pstart, bcount, row_start, csr, N);

    // layers
    k_prep<<<44, 256, 0, stream>>>(W1, as1, ad1, W2, Wt1, Aat1, W2t);
    k_gemm1m<<<(N + 127) / 128, 256, 0, stream>>>(x, (const __fp16*)Wt1, Aat1,
                                                  h1s, als_s, ald1, N);
    int nb1 = ((N + 7) / 8) * 8;   // 8 nodes per block x 8 channel groups
    k_agg1<<<nb1, 256, 0, stream>>>(h1s, als_s, ald1, b1, row_start, csr, out1s, N);
    k_gemm2m<<<(N + 127) / 128, 256, 0, stream>>>(out1s, (const __fp16*)W2t,
                                                  as2, ad2, h2, als2, ald2, N);
    k_agg2<<<(N + 3) / 4, 256, 0, stream>>>(h2, als2, ald2, b2, row_start, csr, (float*)d_out, N);
}

// Round 13
// 141.381 us; speedup vs baseline: 1.3045x; 1.3036x over previous
//
#include <hip/hip_runtime.h>

#define NFEAT 128
#define HEADS 8
#define NHID 16
#define SLOPE 0.2f
#define BSH 8            // 256 dst nodes per bucket; requires N <= 65536 (src fits u16)

typedef __fp16 f16x8 __attribute__((ext_vector_type(8)));   // MFMA A/B frag (4 VGPRs)
typedef __fp16 f16x2 __attribute__((ext_vector_type(2)));
typedef float  f4v   __attribute__((ext_vector_type(4)));   // MFMA C/D frag

__device__ __forceinline__ unsigned pack2h(float a, float b) {
    union { f16x2 h; unsigned u; } r;
    r.h = __builtin_amdgcn_cvt_pkrtz(a, b);
    return r.u;
}
__device__ __forceinline__ f16x2 as_f16x2(unsigned u) {
    union { unsigned u; f16x2 h; } r; r.u = u; return r.h;
}
// build an 8-element fp16 A/B fragment from 8 consecutive f32
__device__ __forceinline__ f16x8 frag_from_f32(const float* p) {
    float4 q0 = *(const float4*)p;
    float4 q1 = *(const float4*)(p + 4);
    union { f16x8 v; f16x2 h[4]; } r;
    r.h[0] = __builtin_amdgcn_cvt_pkrtz(q0.x, q0.y);
    r.h[1] = __builtin_amdgcn_cvt_pkrtz(q0.z, q0.w);
    r.h[2] = __builtin_amdgcn_cvt_pkrtz(q1.x, q1.y);
    r.h[3] = __builtin_amdgcn_cvt_pkrtz(q1.z, q1.w);
    return r.v;
}

// ---------------- bucketed CSR build ----------------

__global__ __launch_bounds__(256) void k_bhist(const int* __restrict__ dst, int E,
                                               int* __restrict__ bcount) {
    __shared__ int h[256];
    int t = threadIdx.x;
    h[t] = 0;
    __syncthreads();
    int stride = gridDim.x * 256;
    for (int i = blockIdx.x * 256 + t; i < E; i += stride)
        atomicAdd(&h[dst[i] >> BSH], 1);
    __syncthreads();
    int v = h[t];
    if (v) atomicAdd(&bcount[t], v);
}

__global__ __launch_bounds__(256) void k_bscan(const int* __restrict__ bcount,
                                               int* __restrict__ pair_start,
                                               int* __restrict__ pair_cursor,
                                               int* __restrict__ row_start,
                                               int E, int n) {
    __shared__ int sh[256];
    int t = threadIdx.x;
    int nb = (n + 255) >> BSH;
    int v = (t < nb) ? bcount[t] : 0;
    sh[t] = v;
    __syncthreads();
    for (int off = 1; off < 256; off <<= 1) {
        int u = (t >= off) ? sh[t - off] : 0;
        __syncthreads();
        sh[t] += u;
        __syncthreads();
    }
    int excl = sh[t] - v;
    pair_start[t] = excl;
    pair_cursor[t] = excl;
    if (t == 0) row_start[n] = E + n;
}

// partition edges into bucket-contiguous packed pairs: {src:16 | dst_local:8}
__global__ __launch_bounds__(256) void k_bscatter(const int* __restrict__ src,
                                                  const int* __restrict__ dst,
                                                  int E, int chunk,
                                                  int* __restrict__ pair_cursor,
                                                  unsigned* __restrict__ pairs) {
    __shared__ int cnt[256], base[256];
    int t = threadIdx.x;
    int beg = blockIdx.x * chunk;
    int end = min(beg + chunk, E);
    if (beg >= end) return;
    cnt[t] = 0;
    __syncthreads();
    for (int i = beg + t; i < end; i += 256)
        atomicAdd(&cnt[dst[i] >> BSH], 1);
    __syncthreads();
    int c = cnt[t];
    base[t] = c ? atomicAdd(&pair_cursor[t], c) : 0;
    __syncthreads();
    cnt[t] = 0;
    __syncthreads();
    for (int i = beg + t; i < end; i += 256) {
        int d = dst[i];
        int b = d >> BSH;
        int ofs = atomicAdd(&cnt[b], 1);
        pairs[base[b] + ofs] = (unsigned)src[i] | ((unsigned)(d & 255) << 16);
    }
}

// per-bucket: degree count (+1 self loop) -> row_start; scatter u16 csr via LDS cursors
__global__ __launch_bounds__(256) void k_bucket_csr(const unsigned* __restrict__ pairs,
                                                    const int* __restrict__ pair_start,
                                                    const int* __restrict__ bcount,
                                                    int* __restrict__ row_start,
                                                    unsigned short* __restrict__ csr, int n) {
    __shared__ int deg[256], sc[256];
    int b = blockIdx.x, t = threadIdx.x;
    int d0 = b << BSH;
    int nd = min(256, n - d0);
    deg[t] = (t < nd) ? 1 : 0;   // self loop
    __syncthreads();
    int pbeg = pair_start[b], pend = pbeg + bcount[b];
    for (int i = pbeg + t; i < pend; i += 256)
        atomicAdd(&deg[(pairs[i] >> 16) & 255], 1);
    __syncthreads();
    int v = deg[t];
    sc[t] = v;
    __syncthreads();
    for (int off = 1; off < 256; off <<= 1) {
        int u = (t >= off) ? sc[t - off] : 0;
        __syncthreads();
        sc[t] += u;
        __syncthreads();
    }
    int excl = sc[t] - v;
    int cbase = pair_start[b] + d0;        // csr base of this bucket
    if (t < nd) row_start[d0 + t] = cbase + excl;
    __syncthreads();
    deg[t] = excl;                          // reuse as cursor
    __syncthreads();
    if (t < nd) {                           // self loop entry
        int pos = atomicAdd(&deg[t], 1);
        csr[cbase + pos] = (unsigned short)(d0 + t);
    }
    for (int i = pbeg + t; i < pend; i += 256) {
        unsigned p = pairs[i];
        int pos = atomicAdd(&deg[(p >> 16) & 255], 1);
        csr[cbase + pos] = (unsigned short)(p & 0xFFFFu);
    }
}

// ---------------- weight prep: Wt1[128c][128k] f16, Aat1[16][128] f16, W2t[16c][128k] f16 ----------------

__global__ __launch_bounds__(256) void k_prep(const float* __restrict__ W1,
                                              const float* __restrict__ as1,
                                              const float* __restrict__ ad1,
                                              const float* __restrict__ W2,
                                              unsigned* __restrict__ Wt1,      // [128][64] u32 (f16x2)
                                              __fp16* __restrict__ Aat1,       // [16][128]
                                              unsigned* __restrict__ W2t) {    // [16][64] u32 (f16x2)
    int t = blockIdx.x * 256 + threadIdx.x;
    if (t < 8192) {
        int c = t >> 6, m = t & 63;
        int k = 2 * m;
        Wt1[t] = pack2h(W1[k * 128 + c], W1[(k + 1) * 128 + c]);
    } else if (t < 10240) {
        int idx = t - 8192;
        int j = idx >> 7, k = idx & 127;
        float v = 0.f;
        if (j < 8)  { if ((k >> 4) == j)     v = as1[k]; }
        else        { if ((k >> 4) == j - 8) v = ad1[k]; }
        Aat1[idx] = (__fp16)v;
    } else if (t < 11264) {
        int idx = t - 10240;
        int c = idx >> 6, m = idx & 63;
        int k = 2 * m;
        W2t[idx] = pack2h(W2[k * 16 + c], W2[(k + 1) * 16 + c]);
    }
}

// ---------------- Layer 1 GEMM via MFMA (f16): h1 = x @ W1, logits via 2nd MFMA ----------------

__global__ __launch_bounds__(256) void k_gemm1m(const float* __restrict__ xf,
                                                const __fp16* __restrict__ Wt,
                                                const __fp16* __restrict__ Aat,
                                                unsigned* __restrict__ h1u,     // [n][64] f16x2
                                                float* __restrict__ als,
                                                float* __restrict__ ald, int n) {
    __shared__ unsigned hl[4][32 * 64];   // per-wave h repack (swizzled), 32 KB
    int tid = threadIdx.x;
    int w = tid >> 6, l = tid & 63;
    int l15 = l & 15, lq = l >> 4;
    int wbase = blockIdx.x * 128 + w * 32;
    f4v acc[2][8] = {};
    int r0 = min(wbase + l15, n - 1);
    int r1 = min(wbase + 16 + l15, n - 1);
#pragma unroll
    for (int kb = 0; kb < 4; ++kb) {
        int ko = kb * 32 + lq * 8;
        f16x8 a0 = frag_from_f32(&xf[(size_t)r0 * 128 + ko]);
        f16x8 a1 = frag_from_f32(&xf[(size_t)r1 * 128 + ko]);
#pragma unroll
        for (int cg = 0; cg < 8; ++cg) {
            f16x8 b = *(const f16x8*)&Wt[(size_t)(cg * 16 + l15) * 128 + ko];
            acc[0][cg] = __builtin_amdgcn_mfma_f32_16x16x32_f16(a0, b, acc[0][cg], 0, 0, 0);
            acc[1][cg] = __builtin_amdgcn_mfma_f32_16x16x32_f16(a1, b, acc[1][cg], 0, 0, 0);
        }
    }
    unsigned* myl = hl[w];
#pragma unroll
    for (int T = 0; T < 2; ++T) {
#pragma unroll
        for (int cg = 0; cg < 8; ++cg) {
#pragma unroll
            for (int j = 0; j < 4; ++j) {
                float v = acc[T][cg][j];
                float vo = __shfl_xor(v, 1);
                if ((l15 & 1) == 0) {
                    int nd = T * 16 + lq * 4 + j;
                    int wd = cg * 8 + (l15 >> 1);
                    int widx = nd * 64 + (((wd >> 2) ^ (nd & 15)) << 2) + (wd & 3);
                    myl[widx] = pack2h(v, vo);
                }
            }
        }
    }
    __syncthreads();
#pragma unroll
    for (int it = 0; it < 8; ++it) {
        int nd = it * 4 + lq;
        int node = wbase + nd;
        uint4 vv = *(const uint4*)&myl[nd * 64 + ((l15 ^ (nd & 15)) << 2)];
        if (node < n) *(uint4*)&h1u[(size_t)node * 64 + l15 * 4] = vv;
    }
#pragma unroll
    for (int T = 0; T < 2; ++T) {
        f4v acca = {};
#pragma unroll
        for (int kb = 0; kb < 4; ++kb) {
            int nd = T * 16 + l15;
            f16x8 ah = *(const f16x8*)&myl[nd * 64 + (((kb * 4 + lq) ^ (nd & 15)) << 2)];
            f16x8 bb = *(const f16x8*)&Aat[l15 * 128 + kb * 32 + lq * 8];
            acca = __builtin_amdgcn_mfma_f32_16x16x32_f16(ah, bb, acca, 0, 0, 0);
        }
#pragma unroll
        for (int j = 0; j < 4; ++j) {
            int node = wbase + T * 16 + lq * 4 + j;
            if (node < n) {
                if (l15 < 8) als[(size_t)node * 8 + l15] = acca[j];
                else         ald[(size_t)node * 8 + (l15 - 8)] = acca[j];
            }
        }
    }
}

// ---------------- Layer 1 aggregation ----------------
// 1 wave per node; 4 edge-groups of 16 lanes; lane lc owns 8 channels (uint4 = 16B f16).
// Edge-pair inner loop: v_perm pairs channels across 2 edges, v_dot2_f32_f16 accumulates in f32.

__global__ __launch_bounds__(256) void k_agg1(const unsigned* __restrict__ hu,
                                              const float* __restrict__ als,
                                              const float* __restrict__ ald,
                                              const float* __restrict__ bias,
                                              const int* __restrict__ row_start,
                                              const unsigned short* __restrict__ csr,
                                              unsigned* __restrict__ out1u, int n) {
    int t = threadIdx.x;
    int l = t & 63;
    int lc = l & 15, eg = l >> 4;
    int nn = blockIdx.x * 4 + (t >> 6);
    if (nn >= n) return;                   // whole wave exits together; no LDS/sync used
    int beg = row_start[nn], end = row_start[nn + 1];
    int len = end - beg;
    int g0 = beg + ((len * eg) >> 2);
    int g1 = beg + ((len * (eg + 1)) >> 2);
    int hd = lc >> 1;
    float aldv = ald[(size_t)nn * 8 + hd];
    float a[8] = {0.f, 0.f, 0.f, 0.f, 0.f, 0.f, 0.f, 0.f};
    float dn = 0.f;
    f16x2 one2; one2[0] = (__fp16)1.f; one2[1] = (__fp16)1.f;
    int i = g0;
    for (; i + 2 <= g1; i += 2) {
        int s0 = csr[i];
        int s1 = csr[i + 1];
        float e0 = als[(size_t)s0 * 8 + hd];
        float e1 = als[(size_t)s1 * 8 + hd];
        uint4 v0 = *(const uint4*)&hu[(size_t)s0 * 64 + lc * 4];
        uint4 v1 = *(const uint4*)&hu[(size_t)s1 * 64 + lc * 4];
        e0 += aldv; e0 = (e0 < 0.f) ? SLOPE * e0 : e0;
        e1 += aldv; e1 = (e1 < 0.f) ? SLOPE * e1 : e1;
        f16x2 xx = __builtin_amdgcn_cvt_pkrtz(__expf(e0), __expf(e1));
        dn = __builtin_amdgcn_fdot2(xx, one2, dn, false);
        unsigned V0[4] = {v0.x, v0.y, v0.z, v0.w};
        unsigned V1[4] = {v1.x, v1.y, v1.z, v1.w};
#pragma unroll
        for (int j = 0; j < 4; ++j) {
            unsigned lo = __builtin_amdgcn_perm(V1[j], V0[j], 0x05040100u);
            unsigned hi = __builtin_amdgcn_perm(V1[j], V0[j], 0x07060302u);
            a[2 * j]     = __builtin_amdgcn_fdot2(xx, as_f16x2(lo), a[2 * j], false);
            a[2 * j + 1] = __builtin_amdgcn_fdot2(xx, as_f16x2(hi), a[2 * j + 1], false);
        }
    }
    if (i < g1) {
        int s0 = csr[i];
        float e0 = als[(size_t)s0 * 8 + hd] + aldv;
        uint4 v0 = *(const uint4*)&hu[(size_t)s0 * 64 + lc * 4];
        e0 = (e0 < 0.f) ? SLOPE * e0 : e0;
        float x0 = __expf(e0);
        dn += x0;
        unsigned V0[4] = {v0.x, v0.y, v0.z, v0.w};
#pragma unroll
        for (int j = 0; j < 4; ++j) {
            f16x2 p = as_f16x2(V0[j]);
            a[2 * j]     = fmaf(x0, (float)p[0], a[2 * j]);
            a[2 * j + 1] = fmaf(x0, (float)p[1], a[2 * j + 1]);
        }
    }
#pragma unroll
    for (int j = 0; j < 8; ++j) {
        a[j] += __shfl_xor(a[j], 16);
        a[j] += __shfl_xor(a[j], 32);
    }
    dn += __shfl_xor(dn, 16);
    dn += __shfl_xor(dn, 32);
    if (eg == 0) {
        float inv = 1.f / dn;
        float4 b0 = *(const float4*)&bias[lc * 8];
        float4 b1 = *(const float4*)&bias[lc * 8 + 4];
        uint4 o;
        o.x = pack2h(fmaxf(a[0] * inv + b0.x, 0.f), fmaxf(a[1] * inv + b0.y, 0.f));
        o.y = pack2h(fmaxf(a[2] * inv + b0.z, 0.f), fmaxf(a[3] * inv + b0.w, 0.f));
        o.z = pack2h(fmaxf(a[4] * inv + b1.x, 0.f), fmaxf(a[5] * inv + b1.y, 0.f));
        o.w = pack2h(fmaxf(a[6] * inv + b1.z, 0.f), fmaxf(a[7] * inv + b1.w, 0.f));
        *(uint4*)&out1u[(size_t)nn * 64 + lc * 4] = o;
    }
}

// ---------------- Layer 2 GEMM via MFMA (f16) ----------------

__global__ __launch_bounds__(256) void k_gemm2m(const __fp16* __restrict__ o1,
                                                const __fp16* __restrict__ W2t,
                                                const float* __restrict__ as2,
                                                const float* __restrict__ ad2,
                                                __fp16* __restrict__ h2,
                                                float* __restrict__ als,
                                                float* __restrict__ ald, int n) {
    int tid = threadIdx.x;
    int w = tid >> 6, l = tid & 63;
    int l15 = l & 15, lq = l >> 4;
    int wbase = blockIdx.x * 128 + w * 32;
    f4v acc[2] = {};
    int r0 = min(wbase + l15, n - 1);
    int r1 = min(wbase + 16 + l15, n - 1);
#pragma unroll
    for (int kb = 0; kb < 4; ++kb) {
        int ko = kb * 32 + lq * 8;
        f16x8 a0 = *(const f16x8*)&o1[(size_t)r0 * 128 + ko];
        f16x8 a1 = *(const f16x8*)&o1[(size_t)r1 * 128 + ko];
        f16x8 b  = *(const f16x8*)&W2t[(size_t)l15 * 128 + ko];
        acc[0] = __builtin_amdgcn_mfma_f32_16x16x32_f16(a0, b, acc[0], 0, 0, 0);
        acc[1] = __builtin_amdgcn_mfma_f32_16x16x32_f16(a1, b, acc[1], 0, 0, 0);
    }
    float asv = as2[l15], adv = ad2[l15];
#pragma unroll
    for (int T = 0; T < 2; ++T) {
#pragma unroll
        for (int j = 0; j < 4; ++j) {
            int node = wbase + T * 16 + lq * 4 + j;
            float hv = acc[T][j];
            float ps = hv * asv, pd = hv * adv;
            ps += __shfl_xor(ps, 1); ps += __shfl_xor(ps, 2);
            ps += __shfl_xor(ps, 4); ps += __shfl_xor(ps, 8);
            pd += __shfl_xor(pd, 1); pd += __shfl_xor(pd, 2);
            pd += __shfl_xor(pd, 4); pd += __shfl_xor(pd, 8);
            if (node < n) {
                h2[(size_t)node * 16 + l15] = (__fp16)hv;
                if (l15 == 0) { als[node] = ps; ald[node] = pd; }
            }
        }
    }
}

// ---------------- Layer 2 aggregation ----------------
// 1 wave per node; 4 edge-groups of 16 lanes; lane lc owns 1 channel (f16 2B of the 32B row).

__global__ __launch_bounds__(256) void k_agg2(const __fp16* __restrict__ h,
                                              const float* __restrict__ als,
                                              const float* __restrict__ ald,
                                              const float* __restrict__ bias,
                                              const int* __restrict__ row_start,
                                              const unsigned short* __restrict__ csr,
                                              float* __restrict__ out, int n) {
    int t = threadIdx.x;
    int l = t & 63;
    int lc = l & 15, eg = l >> 4;
    int nn = blockIdx.x * 4 + (t >> 6);
    if (nn >= n) return;
    int beg = row_start[nn], end = row_start[nn + 1];
    int len = end - beg;
    int g0 = beg + ((len * eg) >> 2);
    int g1 = beg + ((len * (eg + 1)) >> 2);
    float aldv = ald[nn];
    float ac0 = 0.f, ac1 = 0.f, dn0 = 0.f, dn1 = 0.f;
    int i = g0;
    for (; i + 2 <= g1; i += 2) {
        int s0 = csr[i], s1 = csr[i + 1];
        float e0 = als[s0], e1 = als[s1];
        float v0 = (float)h[(size_t)s0 * 16 + lc];
        float v1 = (float)h[(size_t)s1 * 16 + lc];
        e0 += aldv; e0 = (e0 < 0.f) ? SLOPE * e0 : e0;
        e1 += aldv; e1 = (e1 < 0.f) ? SLOPE * e1 : e1;
        float x0 = __expf(e0), x1 = __expf(e1);
        dn0 += x0; dn1 += x1;
        ac0 = fmaf(x0, v0, ac0);
        ac1 = fmaf(x1, v1, ac1);
    }
    if (i < g1) {
        int s0 = csr[i];
        float e0 = als[s0] + aldv;
        e0 = (e0 < 0.f) ? SLOPE * e0 : e0;
        float x0 = __expf(e0);
        dn0 += x0;
        ac0 = fmaf(x0, (float)h[(size_t)s0 * 16 + lc], ac0);
    }
    float ac = ac0 + ac1, dn = dn0 + dn1;
    ac += __shfl_xor(ac, 16); ac += __shfl_xor(ac, 32);
    dn += __shfl_xor(dn, 16); dn += __shfl_xor(dn, 32);
    if (eg == 0) out[(size_t)nn * 16 + lc] = fmaxf(ac / dn + bias[lc], 0.f);
}

// ---------------- launch ----------------

extern "C" void kernel_launch(void* const* d_in, const int* in_sizes, int n_in,
                              void* d_out, int out_size, void* d_ws, size_t ws_size,
                              hipStream_t stream) {
    const float* x   = (const float*)d_in[0];
    const int*   ei  = (const int*)d_in[1];
    const float* W1  = (const float*)d_in[2];
    const float* as1 = (const float*)d_in[3];
    const float* ad1 = (const float*)d_in[4];
    const float* b1  = (const float*)d_in[5];
    const float* W2  = (const float*)d_in[6];
    const float* as2 = (const float*)d_in[7];
    const float* ad2 = (const float*)d_in[8];
    const float* b2  = (const float*)d_in[9];

    int N = in_sizes[0] / NFEAT;
    int E = in_sizes[1] / 2;
    const int* srcp = ei;
    const int* dstp = ei + E;
    int NBUCK = (N + 255) >> BSH;

    char* ws = (char*)d_ws;
    size_t off = 0;
    auto take = [&](size_t bytes) -> char* {
        char* p = ws + off;
        off = (off + bytes + 255) & ~(size_t)255;
        return p;
    };
    int*            row_start = (int*)take((size_t)(N + 1) * 4);
    int*            bcount    = (int*)take(256 * 4);
    int*            pstart    = (int*)take(256 * 4);
    int*            pcursor   = (int*)take(256 * 4);
    unsigned*       pairs     = (unsigned*)take((size_t)E * 4);      // packed {src:16, dlo:8}
    unsigned short* csr       = (unsigned short*)take((size_t)(E + N) * 2);
    unsigned*       Wt1       = (unsigned*)take((size_t)128 * 64 * 4);
    __fp16*         Aat1      = (__fp16*)take((size_t)16 * 128 * 2);
    unsigned*       W2t       = (unsigned*)take((size_t)16 * 64 * 4);
    unsigned*       h1u       = (unsigned*)take((size_t)N * 64 * 4);   // f16x2
    float*          als1      = (float*)take((size_t)N * 8 * 4);
    float*          ald1      = (float*)take((size_t)N * 8 * 4);
    unsigned*       out1u     = (unsigned*)take((size_t)N * 64 * 4);   // f16x2
    __fp16*         h2        = (__fp16*)take((size_t)N * 16 * 2);
    float*          als2      = (float*)take((size_t)N * 4);
    float*          ald2      = (float*)take((size_t)N * 4);

    // CSR build (bucketed counting sort)
    hipMemsetAsync(bcount, 0, 256 * 4, stream);
    k_bhist<<<256, 256, 0, stream>>>(dstp, E, bcount);
    k_bscan<<<1, 256, 0, stream>>>(bcount, pstart, pcursor, row_start, E, N);
    int chunk = (E + 127) / 128;
    k_bscatter<<<128, 256, 0, stream>>>(srcp, dstp, E, chunk, pcursor, pairs);
    k_bucket_csr<<<NBUCK, 256, 0, stream>>>(pairs, pstart, bcount, row_start, csr, N);

    // layers
    k_prep<<<44, 256, 0, stream>>>(W1, as1, ad1, W2, Wt1, Aat1, W2t);
    k_gemm1m<<<(N + 127) / 128, 256, 0, stream>>>(x, (const __fp16*)Wt1, Aat1,
                                                  h1u, als1, ald1, N);
    k_agg1<<<(N + 3) / 4, 256, 0, stream>>>(h1u, als1, ald1, b1, row_start, csr, out1u, N);
    k_gemm2m<<<(N + 127) / 128, 256, 0, stream>>>((const __fp16*)out1u,
                                                  (const __fp16*)W2t,
                                                  as2, ad2, h2, als2, ald2, N);
    k_agg2<<<(N + 3) / 4, 256, 0, stream>>>(h2, als2, ald2, b2, row_start, csr, (float*)d_out, N);
}

// Round 14
// 121.910 us; speedup vs baseline: 1.5129x; 1.1597x over previous
//
#include <hip/hip_runtime.h>

#define NFEAT 128
#define HEADS 8
#define NHID 16
#define SLOPE 0.2f
#define BSH 8            // 256 dst nodes per bucket; requires N <= 65536 (src fits u16)
#define CAPSH 13         // 8192 pairs capacity per bucket (max expected ~4500)

typedef __fp16 f16x8 __attribute__((ext_vector_type(8)));   // MFMA A/B frag (4 VGPRs)
typedef __fp16 f16x2 __attribute__((ext_vector_type(2)));
typedef float  f4v   __attribute__((ext_vector_type(4)));   // MFMA C/D frag

__device__ __forceinline__ unsigned pack2h(float a, float b) {
    union { f16x2 h; unsigned u; } r;
    r.h = __builtin_amdgcn_cvt_pkrtz(a, b);
    return r.u;
}
__device__ __forceinline__ f16x2 as_f16x2(unsigned u) {
    union { unsigned u; f16x2 h; } r; r.u = u; return r.h;
}
__device__ __forceinline__ f16x8 frag_from_f32(const float* p) {
    float4 q0 = *(const float4*)p;
    float4 q1 = *(const float4*)(p + 4);
    union { f16x8 v; f16x2 h[4]; } r;
    r.h[0] = __builtin_amdgcn_cvt_pkrtz(q0.x, q0.y);
    r.h[1] = __builtin_amdgcn_cvt_pkrtz(q0.z, q0.w);
    r.h[2] = __builtin_amdgcn_cvt_pkrtz(q1.x, q1.y);
    r.h[3] = __builtin_amdgcn_cvt_pkrtz(q1.z, q1.w);
    return r.v;
}

// ---------------- CSR build: bscatter into fixed-capacity buckets (no pre-histogram) ----------------

__global__ __launch_bounds__(256) void k_bscatter(const int* __restrict__ src,
                                                  const int* __restrict__ dst,
                                                  int E, int chunk,
                                                  int* __restrict__ bcount,
                                                  unsigned* __restrict__ pairs) {
    __shared__ int cnt[256], base[256];
    int t = threadIdx.x;
    int beg = blockIdx.x * chunk;
    int end = min(beg + chunk, E);
    if (beg >= end) return;
    cnt[t] = 0;
    __syncthreads();
    for (int i = beg + t; i < end; i += 256)
        atomicAdd(&cnt[dst[i] >> BSH], 1);
    __syncthreads();
    int c = cnt[t];
    base[t] = c ? (atomicAdd(&bcount[t], c) + (t << CAPSH)) : 0;
    __syncthreads();
    cnt[t] = 0;
    __syncthreads();
    for (int i = beg + t; i < end; i += 256) {
        int d = dst[i];
        int b = d >> BSH;
        int ofs = atomicAdd(&cnt[b], 1);
        pairs[base[b] + ofs] = (unsigned)src[i] | ((unsigned)(d & 255) << 16);
    }
}

// ---------------- fused: block 0 = bucket-count scan; blocks 1..44 = weight prep ----------------

__global__ __launch_bounds__(256) void k_scan_prep(const int* __restrict__ bcount,
                                                   int* __restrict__ cstart,
                                                   int* __restrict__ row_start,
                                                   int E, int n,
                                                   const float* __restrict__ W1,
                                                   const float* __restrict__ as1,
                                                   const float* __restrict__ ad1,
                                                   const float* __restrict__ W2,
                                                   unsigned* __restrict__ Wt1,
                                                   __fp16* __restrict__ Aat1,
                                                   unsigned* __restrict__ W2t) {
    if (blockIdx.x == 0) {
        __shared__ int sh[256];
        int t = threadIdx.x;
        int nb = (n + 255) >> BSH;
        int v = (t < nb) ? bcount[t] : 0;
        sh[t] = v;
        __syncthreads();
        for (int off = 1; off < 256; off <<= 1) {
            int u = (t >= off) ? sh[t - off] : 0;
            __syncthreads();
            sh[t] += u;
            __syncthreads();
        }
        cstart[t] = sh[t] - v;
        if (t == 0) row_start[n] = E + n;
        return;
    }
    int t = (blockIdx.x - 1) * 256 + threadIdx.x;
    if (t < 8192) {
        int c = t >> 6, m = t & 63;
        int k = 2 * m;
        Wt1[t] = pack2h(W1[k * 128 + c], W1[(k + 1) * 128 + c]);
    } else if (t < 10240) {
        int idx = t - 8192;
        int j = idx >> 7, k = idx & 127;
        float v = 0.f;
        if (j < 8)  { if ((k >> 4) == j)     v = as1[k]; }
        else        { if ((k >> 4) == j - 8) v = ad1[k]; }
        Aat1[idx] = (__fp16)v;
    } else if (t < 11264) {
        int idx = t - 10240;
        int c = idx >> 6, m = idx & 63;
        int k = 2 * m;
        W2t[idx] = pack2h(W2[k * 16 + c], W2[(k + 1) * 16 + c]);
    }
}

// ---------------- fused: blocks [0,nbuck) = per-bucket CSR; blocks [nbuck,..) = layer-1 MFMA GEMM ----------------

__global__ __launch_bounds__(256) void k_csr_gemm1(const unsigned* __restrict__ pairs,
                                                   const int* __restrict__ bcount,
                                                   const int* __restrict__ cstart,
                                                   int* __restrict__ row_start,
                                                   unsigned short* __restrict__ csr,
                                                   const float* __restrict__ xf,
                                                   const __fp16* __restrict__ Wt,
                                                   const __fp16* __restrict__ Aat,
                                                   unsigned* __restrict__ h1u,
                                                   float* __restrict__ als,
                                                   float* __restrict__ ald,
                                                   int n, int nbuck) {
    __shared__ unsigned smem[4][32 * 64];   // 32 KB (gemm repack); csr part aliases 2 KB of it
    if ((int)blockIdx.x < nbuck) {
        int* deg = (int*)&smem[0][0];
        int* sc  = deg + 256;
        int b = blockIdx.x, t = threadIdx.x;
        int d0 = b << BSH;
        int nd = min(256, n - d0);
        deg[t] = (t < nd) ? 1 : 0;   // self loop
        __syncthreads();
        int pbeg = b << CAPSH, pend = pbeg + bcount[b];
        for (int i = pbeg + t; i < pend; i += 256)
            atomicAdd(&deg[(pairs[i] >> 16) & 255], 1);
        __syncthreads();
        int v = deg[t];
        sc[t] = v;
        __syncthreads();
        for (int off = 1; off < 256; off <<= 1) {
            int u = (t >= off) ? sc[t - off] : 0;
            __syncthreads();
            sc[t] += u;
            __syncthreads();
        }
        int excl = sc[t] - v;
        int cbase = cstart[b] + d0;
        if (t < nd) row_start[d0 + t] = cbase + excl;
        __syncthreads();
        deg[t] = excl;                          // reuse as cursor
        __syncthreads();
        if (t < nd) {                           // self loop entry
            int pos = atomicAdd(&deg[t], 1);
            csr[cbase + pos] = (unsigned short)(d0 + t);
        }
        for (int i = pbeg + t; i < pend; i += 256) {
            unsigned p = pairs[i];
            int pos = atomicAdd(&deg[(p >> 16) & 255], 1);
            csr[cbase + pos] = (unsigned short)(p & 0xFFFFu);
        }
        return;
    }
    // ---- gemm1m ----
    int bid = blockIdx.x - nbuck;
    int tid = threadIdx.x;
    int w = tid >> 6, l = tid & 63;
    int l15 = l & 15, lq = l >> 4;
    int wbase = bid * 128 + w * 32;
    f4v acc[2][8] = {};
    int r0 = min(wbase + l15, n - 1);
    int r1 = min(wbase + 16 + l15, n - 1);
#pragma unroll
    for (int kb = 0; kb < 4; ++kb) {
        int ko = kb * 32 + lq * 8;
        f16x8 a0 = frag_from_f32(&xf[(size_t)r0 * 128 + ko]);
        f16x8 a1 = frag_from_f32(&xf[(size_t)r1 * 128 + ko]);
#pragma unroll
        for (int cg = 0; cg < 8; ++cg) {
            f16x8 b = *(const f16x8*)&Wt[(size_t)(cg * 16 + l15) * 128 + ko];
            acc[0][cg] = __builtin_amdgcn_mfma_f32_16x16x32_f16(a0, b, acc[0][cg], 0, 0, 0);
            acc[1][cg] = __builtin_amdgcn_mfma_f32_16x16x32_f16(a1, b, acc[1][cg], 0, 0, 0);
        }
    }
    unsigned* myl = smem[w];
#pragma unroll
    for (int T = 0; T < 2; ++T) {
#pragma unroll
        for (int cg = 0; cg < 8; ++cg) {
#pragma unroll
            for (int j = 0; j < 4; ++j) {
                float v = acc[T][cg][j];
                float vo = __shfl_xor(v, 1);
                if ((l15 & 1) == 0) {
                    int nd = T * 16 + lq * 4 + j;
                    int wd = cg * 8 + (l15 >> 1);
                    int widx = nd * 64 + (((wd >> 2) ^ (nd & 15)) << 2) + (wd & 3);
                    myl[widx] = pack2h(v, vo);
                }
            }
        }
    }
    __syncthreads();
#pragma unroll
    for (int it = 0; it < 8; ++it) {
        int nd = it * 4 + lq;
        int node = wbase + nd;
        uint4 vv = *(const uint4*)&myl[nd * 64 + ((l15 ^ (nd & 15)) << 2)];
        if (node < n) *(uint4*)&h1u[(size_t)node * 64 + l15 * 4] = vv;
    }
#pragma unroll
    for (int T = 0; T < 2; ++T) {
        f4v acca = {};
#pragma unroll
        for (int kb = 0; kb < 4; ++kb) {
            int nd = T * 16 + l15;
            f16x8 ah = *(const f16x8*)&myl[nd * 64 + (((kb * 4 + lq) ^ (nd & 15)) << 2)];
            f16x8 bb = *(const f16x8*)&Aat[l15 * 128 + kb * 32 + lq * 8];
            acca = __builtin_amdgcn_mfma_f32_16x16x32_f16(ah, bb, acca, 0, 0, 0);
        }
#pragma unroll
        for (int j = 0; j < 4; ++j) {
            int node = wbase + T * 16 + lq * 4 + j;
            if (node < n) {
                if (l15 < 8) als[(size_t)node * 8 + l15] = acca[j];
                else         ald[(size_t)node * 8 + (l15 - 8)] = acca[j];
            }
        }
    }
}

// ---------------- Layer 1 aggregation (unroll 4) ----------------
// 1 wave per node; 4 edge-groups of 16 lanes; lane lc owns 8 channels (uint4 = 16B f16).

__global__ __launch_bounds__(256) void k_agg1(const unsigned* __restrict__ hu,
                                              const float* __restrict__ als,
                                              const float* __restrict__ ald,
                                              const float* __restrict__ bias,
                                              const int* __restrict__ row_start,
                                              const unsigned short* __restrict__ csr,
                                              unsigned* __restrict__ out1u, int n) {
    int t = threadIdx.x;
    int l = t & 63;
    int lc = l & 15, eg = l >> 4;
    int nn = blockIdx.x * 4 + (t >> 6);
    if (nn >= n) return;
    int beg = row_start[nn], end = row_start[nn + 1];
    int len = end - beg;
    int g0 = beg + ((len * eg) >> 2);
    int g1 = beg + ((len * (eg + 1)) >> 2);
    int hd = lc >> 1;
    float aldv = ald[(size_t)nn * 8 + hd];
    float a[8] = {0.f, 0.f, 0.f, 0.f, 0.f, 0.f, 0.f, 0.f};
    float dn = 0.f;
    f16x2 one2; one2[0] = (__fp16)1.f; one2[1] = (__fp16)1.f;
    int i = g0;
    for (; i + 4 <= g1; i += 4) {
        int s0 = csr[i], s1 = csr[i + 1], s2 = csr[i + 2], s3 = csr[i + 3];
        float e0 = als[(size_t)s0 * 8 + hd];
        float e1 = als[(size_t)s1 * 8 + hd];
        float e2 = als[(size_t)s2 * 8 + hd];
        float e3 = als[(size_t)s3 * 8 + hd];
        uint4 v0 = *(const uint4*)&hu[(size_t)s0 * 64 + lc * 4];
        uint4 v1 = *(const uint4*)&hu[(size_t)s1 * 64 + lc * 4];
        uint4 v2 = *(const uint4*)&hu[(size_t)s2 * 64 + lc * 4];
        uint4 v3 = *(const uint4*)&hu[(size_t)s3 * 64 + lc * 4];
        e0 += aldv; e0 = (e0 < 0.f) ? SLOPE * e0 : e0;
        e1 += aldv; e1 = (e1 < 0.f) ? SLOPE * e1 : e1;
        e2 += aldv; e2 = (e2 < 0.f) ? SLOPE * e2 : e2;
        e3 += aldv; e3 = (e3 < 0.f) ? SLOPE * e3 : e3;
        f16x2 xa = __builtin_amdgcn_cvt_pkrtz(__expf(e0), __expf(e1));
        f16x2 xb = __builtin_amdgcn_cvt_pkrtz(__expf(e2), __expf(e3));
        dn = __builtin_amdgcn_fdot2(xa, one2, dn, false);
        dn = __builtin_amdgcn_fdot2(xb, one2, dn, false);
        unsigned V0[4] = {v0.x, v0.y, v0.z, v0.w};
        unsigned V1[4] = {v1.x, v1.y, v1.z, v1.w};
        unsigned V2[4] = {v2.x, v2.y, v2.z, v2.w};
        unsigned V3[4] = {v3.x, v3.y, v3.z, v3.w};
#pragma unroll
        for (int j = 0; j < 4; ++j) {
            unsigned lo01 = __builtin_amdgcn_perm(V1[j], V0[j], 0x05040100u);
            unsigned hi01 = __builtin_amdgcn_perm(V1[j], V0[j], 0x07060302u);
            unsigned lo23 = __builtin_amdgcn_perm(V3[j], V2[j], 0x05040100u);
            unsigned hi23 = __builtin_amdgcn_perm(V3[j], V2[j], 0x07060302u);
            a[2 * j]     = __builtin_amdgcn_fdot2(xa, as_f16x2(lo01), a[2 * j], false);
            a[2 * j + 1] = __builtin_amdgcn_fdot2(xa, as_f16x2(hi01), a[2 * j + 1], false);
            a[2 * j]     = __builtin_amdgcn_fdot2(xb, as_f16x2(lo23), a[2 * j], false);
            a[2 * j + 1] = __builtin_amdgcn_fdot2(xb, as_f16x2(hi23), a[2 * j + 1], false);
        }
    }
    for (; i + 2 <= g1; i += 2) {
        int s0 = csr[i];
        int s1 = csr[i + 1];
        float e0 = als[(size_t)s0 * 8 + hd];
        float e1 = als[(size_t)s1 * 8 + hd];
        uint4 v0 = *(const uint4*)&hu[(size_t)s0 * 64 + lc * 4];
        uint4 v1 = *(const uint4*)&hu[(size_t)s1 * 64 + lc * 4];
        e0 += aldv; e0 = (e0 < 0.f) ? SLOPE * e0 : e0;
        e1 += aldv; e1 = (e1 < 0.f) ? SLOPE * e1 : e1;
        f16x2 xx = __builtin_amdgcn_cvt_pkrtz(__expf(e0), __expf(e1));
        dn = __builtin_amdgcn_fdot2(xx, one2, dn, false);
        unsigned V0[4] = {v0.x, v0.y, v0.z, v0.w};
        unsigned V1[4] = {v1.x, v1.y, v1.z, v1.w};
#pragma unroll
        for (int j = 0; j < 4; ++j) {
            unsigned lo = __builtin_amdgcn_perm(V1[j], V0[j], 0x05040100u);
            unsigned hi = __builtin_amdgcn_perm(V1[j], V0[j], 0x07060302u);
            a[2 * j]     = __builtin_amdgcn_fdot2(xx, as_f16x2(lo), a[2 * j], false);
            a[2 * j + 1] = __builtin_amdgcn_fdot2(xx, as_f16x2(hi), a[2 * j + 1], false);
        }
    }
    if (i < g1) {
        int s0 = csr[i];
        float e0 = als[(size_t)s0 * 8 + hd] + aldv;
        uint4 v0 = *(const uint4*)&hu[(size_t)s0 * 64 + lc * 4];
        e0 = (e0 < 0.f) ? SLOPE * e0 : e0;
        float x0 = __expf(e0);
        dn += x0;
        unsigned V0[4] = {v0.x, v0.y, v0.z, v0.w};
#pragma unroll
        for (int j = 0; j < 4; ++j) {
            f16x2 p = as_f16x2(V0[j]);
            a[2 * j]     = fmaf(x0, (float)p[0], a[2 * j]);
            a[2 * j + 1] = fmaf(x0, (float)p[1], a[2 * j + 1]);
        }
    }
#pragma unroll
    for (int j = 0; j < 8; ++j) {
        a[j] += __shfl_xor(a[j], 16);
        a[j] += __shfl_xor(a[j], 32);
    }
    dn += __shfl_xor(dn, 16);
    dn += __shfl_xor(dn, 32);
    if (eg == 0) {
        float inv = 1.f / dn;
        float4 b0 = *(const float4*)&bias[lc * 8];
        float4 b1 = *(const float4*)&bias[lc * 8 + 4];
        uint4 o;
        o.x = pack2h(fmaxf(a[0] * inv + b0.x, 0.f), fmaxf(a[1] * inv + b0.y, 0.f));
        o.y = pack2h(fmaxf(a[2] * inv + b0.z, 0.f), fmaxf(a[3] * inv + b0.w, 0.f));
        o.z = pack2h(fmaxf(a[4] * inv + b1.x, 0.f), fmaxf(a[5] * inv + b1.y, 0.f));
        o.w = pack2h(fmaxf(a[6] * inv + b1.z, 0.f), fmaxf(a[7] * inv + b1.w, 0.f));
        *(uint4*)&out1u[(size_t)nn * 64 + lc * 4] = o;
    }
}

// ---------------- Layer 2 GEMM via MFMA (f16) ----------------

__global__ __launch_bounds__(256) void k_gemm2m(const __fp16* __restrict__ o1,
                                                const __fp16* __restrict__ W2t,
                                                const float* __restrict__ as2,
                                                const float* __restrict__ ad2,
                                                __fp16* __restrict__ h2,
                                                float* __restrict__ als,
                                                float* __restrict__ ald, int n) {
    int tid = threadIdx.x;
    int w = tid >> 6, l = tid & 63;
    int l15 = l & 15, lq = l >> 4;
    int wbase = blockIdx.x * 128 + w * 32;
    f4v acc[2] = {};
    int r0 = min(wbase + l15, n - 1);
    int r1 = min(wbase + 16 + l15, n - 1);
#pragma unroll
    for (int kb = 0; kb < 4; ++kb) {
        int ko = kb * 32 + lq * 8;
        f16x8 a0 = *(const f16x8*)&o1[(size_t)r0 * 128 + ko];
        f16x8 a1 = *(const f16x8*)&o1[(size_t)r1 * 128 + ko];
        f16x8 b  = *(const f16x8*)&W2t[(size_t)l15 * 128 + ko];
        acc[0] = __builtin_amdgcn_mfma_f32_16x16x32_f16(a0, b, acc[0], 0, 0, 0);
        acc[1] = __builtin_amdgcn_mfma_f32_16x16x32_f16(a1, b, acc[1], 0, 0, 0);
    }
    float asv = as2[l15], adv = ad2[l15];
#pragma unroll
    for (int T = 0; T < 2; ++T) {
#pragma unroll
        for (int j = 0; j < 4; ++j) {
            int node = wbase + T * 16 + lq * 4 + j;
            float hv = acc[T][j];
            float ps = hv * asv, pd = hv * adv;
            ps += __shfl_xor(ps, 1); ps += __shfl_xor(ps, 2);
            ps += __shfl_xor(ps, 4); ps += __shfl_xor(ps, 8);
            pd += __shfl_xor(pd, 1); pd += __shfl_xor(pd, 2);
            pd += __shfl_xor(pd, 4); pd += __shfl_xor(pd, 8);
            if (node < n) {
                h2[(size_t)node * 16 + l15] = (__fp16)hv;
                if (l15 == 0) { als[node] = ps; ald[node] = pd; }
            }
        }
    }
}

// ---------------- Layer 2 aggregation (unroll 4) ----------------

__global__ __launch_bounds__(256) void k_agg2(const __fp16* __restrict__ h,
                                              const float* __restrict__ als,
                                              const float* __restrict__ ald,
                                              const float* __restrict__ bias,
                                              const int* __restrict__ row_start,
                                              const unsigned short* __restrict__ csr,
                                              float* __restrict__ out, int n) {
    int t = threadIdx.x;
    int l = t & 63;
    int lc = l & 15, eg = l >> 4;
    int nn = blockIdx.x * 4 + (t >> 6);
    if (nn >= n) return;
    int beg = row_start[nn], end = row_start[nn + 1];
    int len = end - beg;
    int g0 = beg + ((len * eg) >> 2);
    int g1 = beg + ((len * (eg + 1)) >> 2);
    float aldv = ald[nn];
    float ac0 = 0.f, ac1 = 0.f, ac2 = 0.f, ac3 = 0.f;
    float dn0 = 0.f, dn1 = 0.f, dn2 = 0.f, dn3 = 0.f;
    int i = g0;
    for (; i + 4 <= g1; i += 4) {
        int s0 = csr[i], s1 = csr[i + 1], s2 = csr[i + 2], s3 = csr[i + 3];
        float e0 = als[s0], e1 = als[s1], e2 = als[s2], e3 = als[s3];
        float v0 = (float)h[(size_t)s0 * 16 + lc];
        float v1 = (float)h[(size_t)s1 * 16 + lc];
        float v2 = (float)h[(size_t)s2 * 16 + lc];
        float v3 = (float)h[(size_t)s3 * 16 + lc];
        e0 += aldv; e0 = (e0 < 0.f) ? SLOPE * e0 : e0;
        e1 += aldv; e1 = (e1 < 0.f) ? SLOPE * e1 : e1;
        e2 += aldv; e2 = (e2 < 0.f) ? SLOPE * e2 : e2;
        e3 += aldv; e3 = (e3 < 0.f) ? SLOPE * e3 : e3;
        float x0 = __expf(e0), x1 = __expf(e1), x2 = __expf(e2), x3 = __expf(e3);
        dn0 += x0; dn1 += x1; dn2 += x2; dn3 += x3;
        ac0 = fmaf(x0, v0, ac0);
        ac1 = fmaf(x1, v1, ac1);
        ac2 = fmaf(x2, v2, ac2);
        ac3 = fmaf(x3, v3, ac3);
    }
    for (; i < g1; ++i) {
        int s0 = csr[i];
        float e0 = als[s0] + aldv;
        e0 = (e0 < 0.f) ? SLOPE * e0 : e0;
        float x0 = __expf(e0);
        dn0 += x0;
        ac0 = fmaf(x0, (float)h[(size_t)s0 * 16 + lc], ac0);
    }
    float ac = (ac0 + ac1) + (ac2 + ac3);
    float dn = (dn0 + dn1) + (dn2 + dn3);
    ac += __shfl_xor(ac, 16); ac += __shfl_xor(ac, 32);
    dn += __shfl_xor(dn, 16); dn += __shfl_xor(dn, 32);
    if (eg == 0) out[(size_t)nn * 16 + lc] = fmaxf(ac / dn + bias[lc], 0.f);
}

// ---------------- launch ----------------

extern "C" void kernel_launch(void* const* d_in, const int* in_sizes, int n_in,
                              void* d_out, int out_size, void* d_ws, size_t ws_size,
                              hipStream_t stream) {
    const float* x   = (const float*)d_in[0];
    const int*   ei  = (const int*)d_in[1];
    const float* W1  = (const float*)d_in[2];
    const float* as1 = (const float*)d_in[3];
    const float* ad1 = (const float*)d_in[4];
    const float* b1  = (const float*)d_in[5];
    const float* W2  = (const float*)d_in[6];
    const float* as2 = (const float*)d_in[7];
    const float* ad2 = (const float*)d_in[8];
    const float* b2  = (const float*)d_in[9];

    int N = in_sizes[0] / NFEAT;
    int E = in_sizes[1] / 2;
    const int* srcp = ei;
    const int* dstp = ei + E;
    int NBUCK = (N + 255) >> BSH;
    int NBg = (N + 127) / 128;

    char* ws = (char*)d_ws;
    size_t off = 0;
    auto take = [&](size_t bytes) -> char* {
        char* p = ws + off;
        off = (off + bytes + 255) & ~(size_t)255;
        return p;
    };
    int*            row_start = (int*)take((size_t)(N + 1) * 4);
    int*            bcount    = (int*)take(256 * 4);
    int*            cstart    = (int*)take(256 * 4);
    unsigned*       pairs     = (unsigned*)take((size_t)256 << (CAPSH + 2));   // 8 MB
    unsigned short* csr       = (unsigned short*)take((size_t)(E + N) * 2);
    unsigned*       Wt1       = (unsigned*)take((size_t)128 * 64 * 4);
    __fp16*         Aat1      = (__fp16*)take((size_t)16 * 128 * 2);
    unsigned*       W2t       = (unsigned*)take((size_t)16 * 64 * 4);
    unsigned*       h1u       = (unsigned*)take((size_t)N * 64 * 4);   // f16x2
    float*          als1      = (float*)take((size_t)N * 8 * 4);
    float*          ald1      = (float*)take((size_t)N * 8 * 4);
    unsigned*       out1u     = (unsigned*)take((size_t)N * 64 * 4);   // f16x2
    __fp16*         h2        = (__fp16*)take((size_t)N * 16 * 2);
    float*          als2      = (float*)take((size_t)N * 4);
    float*          ald2      = (float*)take((size_t)N * 4);

    hipMemsetAsync(bcount, 0, 256 * 4, stream);
    int chunk = (E + 127) / 128;
    k_bscatter<<<128, 256, 0, stream>>>(srcp, dstp, E, chunk, bcount, pairs);
    k_scan_prep<<<45, 256, 0, stream>>>(bcount, cstart, row_start, E, N,
                                        W1, as1, ad1, W2, Wt1, Aat1, W2t);
    k_csr_gemm1<<<NBUCK + NBg, 256, 0, stream>>>(pairs, bcount, cstart, row_start, csr,
                                                 x, (const __fp16*)Wt1, Aat1,
                                                 h1u, als1, ald1, N, NBUCK);
    k_agg1<<<(N + 3) / 4, 256, 0, stream>>>(h1u, als1, ald1, b1, row_start, csr, out1u, N);
    k_gemm2m<<<NBg, 256, 0, stream>>>((const __fp16*)out1u, (const __fp16*)W2t,
                                      as2, ad2, h2, als2, ald2, N);
    k_agg2<<<(N + 3) / 4, 256, 0, stream>>>(h2, als2, ald2, b2, row_start, csr, (float*)d_out, N);
}

// Round 15
// 120.532 us; speedup vs baseline: 1.5302x; 1.0114x over previous
//
#include <hip/hip_runtime.h>

#define NFEAT 128
#define HEADS 8
#define NHID 16
#define SLOPE 0.2f
#define BSH 8            // 256 dst nodes per bucket; requires N <= 65536 (src fits u16)
#define CAPSH 13         // 8192 pairs capacity per bucket (max expected ~4500)

typedef __fp16 f16x8 __attribute__((ext_vector_type(8)));   // MFMA A/B frag (4 VGPRs)
typedef __fp16 f16x2 __attribute__((ext_vector_type(2)));
typedef float  f4v   __attribute__((ext_vector_type(4)));   // MFMA C/D frag

__device__ __forceinline__ unsigned pack2h(float a, float b) {
    union { f16x2 h; unsigned u; } r;
    r.h = __builtin_amdgcn_cvt_pkrtz(a, b);
    return r.u;
}
__device__ __forceinline__ f16x2 as_f16x2(unsigned u) {
    union { unsigned u; f16x2 h; } r; r.u = u; return r.h;
}
__device__ __forceinline__ f16x8 frag_from_f32(const float* p) {
    float4 q0 = *(const float4*)p;
    float4 q1 = *(const float4*)(p + 4);
    union { f16x8 v; f16x2 h[4]; } r;
    r.h[0] = __builtin_amdgcn_cvt_pkrtz(q0.x, q0.y);
    r.h[1] = __builtin_amdgcn_cvt_pkrtz(q0.z, q0.w);
    r.h[2] = __builtin_amdgcn_cvt_pkrtz(q1.x, q1.y);
    r.h[3] = __builtin_amdgcn_cvt_pkrtz(q1.z, q1.w);
    return r.v;
}

// ---------------- CSR build: bscatter into fixed-capacity buckets (no pre-histogram) ----------------

__global__ __launch_bounds__(256) void k_bscatter(const int* __restrict__ src,
                                                  const int* __restrict__ dst,
                                                  int E, int chunk,
                                                  int* __restrict__ bcount,
                                                  unsigned* __restrict__ pairs) {
    __shared__ int cnt[256], base[256];
    int t = threadIdx.x;
    int beg = blockIdx.x * chunk;
    int end = min(beg + chunk, E);
    if (beg >= end) return;
    cnt[t] = 0;
    __syncthreads();
    for (int i = beg + t; i < end; i += 256)
        atomicAdd(&cnt[dst[i] >> BSH], 1);
    __syncthreads();
    int c = cnt[t];
    base[t] = c ? (atomicAdd(&bcount[t], c) + (t << CAPSH)) : 0;
    __syncthreads();
    cnt[t] = 0;
    __syncthreads();
    for (int i = beg + t; i < end; i += 256) {
        int d = dst[i];
        int b = d >> BSH;
        int ofs = atomicAdd(&cnt[b], 1);
        pairs[base[b] + ofs] = (unsigned)src[i] | ((unsigned)(d & 255) << 16);
    }
}

// ---------------- fused: block 0 = bucket-count scan; blocks 1..44 = weight prep ----------------

__global__ __launch_bounds__(256) void k_scan_prep(const int* __restrict__ bcount,
                                                   int* __restrict__ cstart,
                                                   int* __restrict__ row_start,
                                                   int E, int n,
                                                   const float* __restrict__ W1,
                                                   const float* __restrict__ as1,
                                                   const float* __restrict__ ad1,
                                                   const float* __restrict__ W2,
                                                   unsigned* __restrict__ Wt1,
                                                   __fp16* __restrict__ Aat1,
                                                   unsigned* __restrict__ W2t) {
    if (blockIdx.x == 0) {
        __shared__ int sh[256];
        int t = threadIdx.x;
        int nb = (n + 255) >> BSH;
        int v = (t < nb) ? bcount[t] : 0;
        sh[t] = v;
        __syncthreads();
        for (int off = 1; off < 256; off <<= 1) {
            int u = (t >= off) ? sh[t - off] : 0;
            __syncthreads();
            sh[t] += u;
            __syncthreads();
        }
        cstart[t] = sh[t] - v;
        if (t == 0) row_start[n] = E + n;
        return;
    }
    int t = (blockIdx.x - 1) * 256 + threadIdx.x;
    if (t < 8192) {
        int c = t >> 6, m = t & 63;
        int k = 2 * m;
        Wt1[t] = pack2h(W1[k * 128 + c], W1[(k + 1) * 128 + c]);
    } else if (t < 10240) {
        int idx = t - 8192;
        int j = idx >> 7, k = idx & 127;
        float v = 0.f;
        if (j < 8)  { if ((k >> 4) == j)     v = as1[k]; }
        else        { if ((k >> 4) == j - 8) v = ad1[k]; }
        Aat1[idx] = (__fp16)v;
    } else if (t < 11264) {
        int idx = t - 10240;
        int c = idx >> 6, m = idx & 63;
        int k = 2 * m;
        W2t[idx] = pack2h(W2[k * 16 + c], W2[(k + 1) * 16 + c]);
    }
}

// ---------------- fused: blocks [0,nbuck) = per-bucket CSR; blocks [nbuck,..) = layer-1 MFMA GEMM ----------------

__global__ __launch_bounds__(256) void k_csr_gemm1(const unsigned* __restrict__ pairs,
                                                   const int* __restrict__ bcount,
                                                   const int* __restrict__ cstart,
                                                   int* __restrict__ row_start,
                                                   unsigned short* __restrict__ csr,
                                                   const float* __restrict__ xf,
                                                   const __fp16* __restrict__ Wt,
                                                   const __fp16* __restrict__ Aat,
                                                   unsigned* __restrict__ h1u,
                                                   float* __restrict__ als,
                                                   float* __restrict__ ald,
                                                   int n, int nbuck) {
    __shared__ unsigned smem[4][32 * 64];   // 32 KB (gemm repack); csr part aliases 2 KB of it
    if ((int)blockIdx.x < nbuck) {
        int* deg = (int*)&smem[0][0];
        int* sc  = deg + 256;
        int b = blockIdx.x, t = threadIdx.x;
        int d0 = b << BSH;
        int nd = min(256, n - d0);
        deg[t] = (t < nd) ? 1 : 0;   // self loop
        __syncthreads();
        int pbeg = b << CAPSH, pend = pbeg + bcount[b];
        for (int i = pbeg + t; i < pend; i += 256)
            atomicAdd(&deg[(pairs[i] >> 16) & 255], 1);
        __syncthreads();
        int v = deg[t];
        sc[t] = v;
        __syncthreads();
        for (int off = 1; off < 256; off <<= 1) {
            int u = (t >= off) ? sc[t - off] : 0;
            __syncthreads();
            sc[t] += u;
            __syncthreads();
        }
        int excl = sc[t] - v;
        int cbase = cstart[b] + d0;
        if (t < nd) row_start[d0 + t] = cbase + excl;
        __syncthreads();
        deg[t] = excl;                          // reuse as cursor
        __syncthreads();
        if (t < nd) {                           // self loop entry
            int pos = atomicAdd(&deg[t], 1);
            csr[cbase + pos] = (unsigned short)(d0 + t);
        }
        for (int i = pbeg + t; i < pend; i += 256) {
            unsigned p = pairs[i];
            int pos = atomicAdd(&deg[(p >> 16) & 255], 1);
            csr[cbase + pos] = (unsigned short)(p & 0xFFFFu);
        }
        return;
    }
    // ---- gemm1m ----
    int bid = blockIdx.x - nbuck;
    int tid = threadIdx.x;
    int w = tid >> 6, l = tid & 63;
    int l15 = l & 15, lq = l >> 4;
    int wbase = bid * 128 + w * 32;
    f4v acc[2][8] = {};
    int r0 = min(wbase + l15, n - 1);
    int r1 = min(wbase + 16 + l15, n - 1);
#pragma unroll
    for (int kb = 0; kb < 4; ++kb) {
        int ko = kb * 32 + lq * 8;
        f16x8 a0 = frag_from_f32(&xf[(size_t)r0 * 128 + ko]);
        f16x8 a1 = frag_from_f32(&xf[(size_t)r1 * 128 + ko]);
#pragma unroll
        for (int cg = 0; cg < 8; ++cg) {
            f16x8 b = *(const f16x8*)&Wt[(size_t)(cg * 16 + l15) * 128 + ko];
            acc[0][cg] = __builtin_amdgcn_mfma_f32_16x16x32_f16(a0, b, acc[0][cg], 0, 0, 0);
            acc[1][cg] = __builtin_amdgcn_mfma_f32_16x16x32_f16(a1, b, acc[1][cg], 0, 0, 0);
        }
    }
    unsigned* myl = smem[w];
#pragma unroll
    for (int T = 0; T < 2; ++T) {
#pragma unroll
        for (int cg = 0; cg < 8; ++cg) {
#pragma unroll
            for (int j = 0; j < 4; ++j) {
                float v = acc[T][cg][j];
                float vo = __shfl_xor(v, 1);
                if ((l15 & 1) == 0) {
                    int nd = T * 16 + lq * 4 + j;
                    int wd = cg * 8 + (l15 >> 1);
                    int widx = nd * 64 + (((wd >> 2) ^ (nd & 15)) << 2) + (wd & 3);
                    myl[widx] = pack2h(v, vo);
                }
            }
        }
    }
    __syncthreads();
#pragma unroll
    for (int it = 0; it < 8; ++it) {
        int nd = it * 4 + lq;
        int node = wbase + nd;
        uint4 vv = *(const uint4*)&myl[nd * 64 + ((l15 ^ (nd & 15)) << 2)];
        if (node < n) *(uint4*)&h1u[(size_t)node * 64 + l15 * 4] = vv;
    }
#pragma unroll
    for (int T = 0; T < 2; ++T) {
        f4v acca = {};
#pragma unroll
        for (int kb = 0; kb < 4; ++kb) {
            int nd = T * 16 + l15;
            f16x8 ah = *(const f16x8*)&myl[nd * 64 + (((kb * 4 + lq) ^ (nd & 15)) << 2)];
            f16x8 bb = *(const f16x8*)&Aat[l15 * 128 + kb * 32 + lq * 8];
            acca = __builtin_amdgcn_mfma_f32_16x16x32_f16(ah, bb, acca, 0, 0, 0);
        }
#pragma unroll
        for (int j = 0; j < 4; ++j) {
            int node = wbase + T * 16 + lq * 4 + j;
            if (node < n) {
                if (l15 < 8) als[(size_t)node * 8 + l15] = acca[j];
                else         ald[(size_t)node * 8 + (l15 - 8)] = acca[j];
            }
        }
    }
}

// ---------------- Layer 1 aggregation (unroll 4) + fused layer-2 GEMM/logits epilogue ----------------
// 1 wave per node; 4 edge-groups of 16 lanes; lane lc owns 8 channels (uint4 = 16B f16).
// Epilogue: out1 row -> per-wave LDS -> h2[16] via v_dot2 against W2t; als2/ald2 via shuffle reduce.

__global__ __launch_bounds__(256) void k_agg1(const unsigned* __restrict__ hu,
                                              const float* __restrict__ als,
                                              const float* __restrict__ ald,
                                              const float* __restrict__ bias,
                                              const int* __restrict__ row_start,
                                              const unsigned short* __restrict__ csr,
                                              const unsigned* __restrict__ W2t,   // [16][64] u32
                                              const float* __restrict__ as2,
                                              const float* __restrict__ ad2,
                                              __fp16* __restrict__ h2,
                                              float* __restrict__ als2,
                                              float* __restrict__ ald2, int n) {
    __shared__ unsigned lrow[4][64];   // per-wave out1 row (f16x2 words)
    int t = threadIdx.x;
    int w = t >> 6;
    int l = t & 63;
    int lc = l & 15, eg = l >> 4;
    int nn = blockIdx.x * 4 + w;
    if (nn >= n) return;
    int beg = row_start[nn], end = row_start[nn + 1];
    int len = end - beg;
    int g0 = beg + ((len * eg) >> 2);
    int g1 = beg + ((len * (eg + 1)) >> 2);
    int hd = lc >> 1;
    float aldv = ald[(size_t)nn * 8 + hd];
    float a[8] = {0.f, 0.f, 0.f, 0.f, 0.f, 0.f, 0.f, 0.f};
    float dn = 0.f;
    f16x2 one2; one2[0] = (__fp16)1.f; one2[1] = (__fp16)1.f;
    int i = g0;
    for (; i + 4 <= g1; i += 4) {
        int s0 = csr[i], s1 = csr[i + 1], s2 = csr[i + 2], s3 = csr[i + 3];
        float e0 = als[(size_t)s0 * 8 + hd];
        float e1 = als[(size_t)s1 * 8 + hd];
        float e2 = als[(size_t)s2 * 8 + hd];
        float e3 = als[(size_t)s3 * 8 + hd];
        uint4 v0 = *(const uint4*)&hu[(size_t)s0 * 64 + lc * 4];
        uint4 v1 = *(const uint4*)&hu[(size_t)s1 * 64 + lc * 4];
        uint4 v2 = *(const uint4*)&hu[(size_t)s2 * 64 + lc * 4];
        uint4 v3 = *(const uint4*)&hu[(size_t)s3 * 64 + lc * 4];
        e0 += aldv; e0 = (e0 < 0.f) ? SLOPE * e0 : e0;
        e1 += aldv; e1 = (e1 < 0.f) ? SLOPE * e1 : e1;
        e2 += aldv; e2 = (e2 < 0.f) ? SLOPE * e2 : e2;
        e3 += aldv; e3 = (e3 < 0.f) ? SLOPE * e3 : e3;
        f16x2 xa = __builtin_amdgcn_cvt_pkrtz(__expf(e0), __expf(e1));
        f16x2 xb = __builtin_amdgcn_cvt_pkrtz(__expf(e2), __expf(e3));
        dn = __builtin_amdgcn_fdot2(xa, one2, dn, false);
        dn = __builtin_amdgcn_fdot2(xb, one2, dn, false);
        unsigned V0[4] = {v0.x, v0.y, v0.z, v0.w};
        unsigned V1[4] = {v1.x, v1.y, v1.z, v1.w};
        unsigned V2[4] = {v2.x, v2.y, v2.z, v2.w};
        unsigned V3[4] = {v3.x, v3.y, v3.z, v3.w};
#pragma unroll
        for (int j = 0; j < 4; ++j) {
            unsigned lo01 = __builtin_amdgcn_perm(V1[j], V0[j], 0x05040100u);
            unsigned hi01 = __builtin_amdgcn_perm(V1[j], V0[j], 0x07060302u);
            unsigned lo23 = __builtin_amdgcn_perm(V3[j], V2[j], 0x05040100u);
            unsigned hi23 = __builtin_amdgcn_perm(V3[j], V2[j], 0x07060302u);
            a[2 * j]     = __builtin_amdgcn_fdot2(xa, as_f16x2(lo01), a[2 * j], false);
            a[2 * j + 1] = __builtin_amdgcn_fdot2(xa, as_f16x2(hi01), a[2 * j + 1], false);
            a[2 * j]     = __builtin_amdgcn_fdot2(xb, as_f16x2(lo23), a[2 * j], false);
            a[2 * j + 1] = __builtin_amdgcn_fdot2(xb, as_f16x2(hi23), a[2 * j + 1], false);
        }
    }
    for (; i + 2 <= g1; i += 2) {
        int s0 = csr[i];
        int s1 = csr[i + 1];
        float e0 = als[(size_t)s0 * 8 + hd];
        float e1 = als[(size_t)s1 * 8 + hd];
        uint4 v0 = *(const uint4*)&hu[(size_t)s0 * 64 + lc * 4];
        uint4 v1 = *(const uint4*)&hu[(size_t)s1 * 64 + lc * 4];
        e0 += aldv; e0 = (e0 < 0.f) ? SLOPE * e0 : e0;
        e1 += aldv; e1 = (e1 < 0.f) ? SLOPE * e1 : e1;
        f16x2 xx = __builtin_amdgcn_cvt_pkrtz(__expf(e0), __expf(e1));
        dn = __builtin_amdgcn_fdot2(xx, one2, dn, false);
        unsigned V0[4] = {v0.x, v0.y, v0.z, v0.w};
        unsigned V1[4] = {v1.x, v1.y, v1.z, v1.w};
#pragma unroll
        for (int j = 0; j < 4; ++j) {
            unsigned lo = __builtin_amdgcn_perm(V1[j], V0[j], 0x05040100u);
            unsigned hi = __builtin_amdgcn_perm(V1[j], V0[j], 0x07060302u);
            a[2 * j]     = __builtin_amdgcn_fdot2(xx, as_f16x2(lo), a[2 * j], false);
            a[2 * j + 1] = __builtin_amdgcn_fdot2(xx, as_f16x2(hi), a[2 * j + 1], false);
        }
    }
    if (i < g1) {
        int s0 = csr[i];
        float e0 = als[(size_t)s0 * 8 + hd] + aldv;
        uint4 v0 = *(const uint4*)&hu[(size_t)s0 * 64 + lc * 4];
        e0 = (e0 < 0.f) ? SLOPE * e0 : e0;
        float x0 = __expf(e0);
        dn += x0;
        unsigned V0[4] = {v0.x, v0.y, v0.z, v0.w};
#pragma unroll
        for (int j = 0; j < 4; ++j) {
            f16x2 p = as_f16x2(V0[j]);
            a[2 * j]     = fmaf(x0, (float)p[0], a[2 * j]);
            a[2 * j + 1] = fmaf(x0, (float)p[1], a[2 * j + 1]);
        }
    }
#pragma unroll
    for (int j = 0; j < 8; ++j) {
        a[j] += __shfl_xor(a[j], 16);
        a[j] += __shfl_xor(a[j], 32);
    }
    dn += __shfl_xor(dn, 16);
    dn += __shfl_xor(dn, 32);
    // out1 row (relu'd, biased, f16) -> per-wave LDS
    float inv = 1.f / dn;
    if (eg == 0) {
        float4 b0 = *(const float4*)&bias[lc * 8];
        float4 b1 = *(const float4*)&bias[lc * 8 + 4];
        uint4 o;
        o.x = pack2h(fmaxf(a[0] * inv + b0.x, 0.f), fmaxf(a[1] * inv + b0.y, 0.f));
        o.y = pack2h(fmaxf(a[2] * inv + b0.z, 0.f), fmaxf(a[3] * inv + b0.w, 0.f));
        o.z = pack2h(fmaxf(a[4] * inv + b1.x, 0.f), fmaxf(a[5] * inv + b1.y, 0.f));
        o.w = pack2h(fmaxf(a[6] * inv + b1.z, 0.f), fmaxf(a[7] * inv + b1.w, 0.f));
        *(uint4*)&lrow[w][lc * 4] = o;
    }
    // fused layer-2: lane (eg,lc) computes quarter-dot of h2[lc] over k = eg*32..eg*32+31
    const uint4* rp = (const uint4*)&lrow[w][eg * 16];      // same-wave LDS, no barrier
    const uint4* wp = (const uint4*)&W2t[lc * 64 + eg * 16];
    float hp = 0.f;
#pragma unroll
    for (int q = 0; q < 4; ++q) {
        uint4 rv = rp[q];
        uint4 wv = wp[q];
        hp = __builtin_amdgcn_fdot2(as_f16x2(rv.x), as_f16x2(wv.x), hp, false);
        hp = __builtin_amdgcn_fdot2(as_f16x2(rv.y), as_f16x2(wv.y), hp, false);
        hp = __builtin_amdgcn_fdot2(as_f16x2(rv.z), as_f16x2(wv.z), hp, false);
        hp = __builtin_amdgcn_fdot2(as_f16x2(rv.w), as_f16x2(wv.w), hp, false);
    }
    hp += __shfl_xor(hp, 16);
    hp += __shfl_xor(hp, 32);
    float ps = hp * as2[lc];
    float pd = hp * ad2[lc];
    ps += __shfl_xor(ps, 1); ps += __shfl_xor(ps, 2);
    ps += __shfl_xor(ps, 4); ps += __shfl_xor(ps, 8);
    pd += __shfl_xor(pd, 1); pd += __shfl_xor(pd, 2);
    pd += __shfl_xor(pd, 4); pd += __shfl_xor(pd, 8);
    if (eg == 0) h2[(size_t)nn * 16 + lc] = (__fp16)hp;
    if (l == 0) { als2[nn] = ps; ald2[nn] = pd; }
}

// ---------------- Layer 2 aggregation (unroll 4) ----------------

__global__ __launch_bounds__(256) void k_agg2(const __fp16* __restrict__ h,
                                              const float* __restrict__ als,
                                              const float* __restrict__ ald,
                                              const float* __restrict__ bias,
                                              const int* __restrict__ row_start,
                                              const unsigned short* __restrict__ csr,
                                              float* __restrict__ out, int n) {
    int t = threadIdx.x;
    int l = t & 63;
    int lc = l & 15, eg = l >> 4;
    int nn = blockIdx.x * 4 + (t >> 6);
    if (nn >= n) return;
    int beg = row_start[nn], end = row_start[nn + 1];
    int len = end - beg;
    int g0 = beg + ((len * eg) >> 2);
    int g1 = beg + ((len * (eg + 1)) >> 2);
    float aldv = ald[nn];
    float ac0 = 0.f, ac1 = 0.f, ac2 = 0.f, ac3 = 0.f;
    float dn0 = 0.f, dn1 = 0.f, dn2 = 0.f, dn3 = 0.f;
    int i = g0;
    for (; i + 4 <= g1; i += 4) {
        int s0 = csr[i], s1 = csr[i + 1], s2 = csr[i + 2], s3 = csr[i + 3];
        float e0 = als[s0], e1 = als[s1], e2 = als[s2], e3 = als[s3];
        float v0 = (float)h[(size_t)s0 * 16 + lc];
        float v1 = (float)h[(size_t)s1 * 16 + lc];
        float v2 = (float)h[(size_t)s2 * 16 + lc];
        float v3 = (float)h[(size_t)s3 * 16 + lc];
        e0 += aldv; e0 = (e0 < 0.f) ? SLOPE * e0 : e0;
        e1 += aldv; e1 = (e1 < 0.f) ? SLOPE * e1 : e1;
        e2 += aldv; e2 = (e2 < 0.f) ? SLOPE * e2 : e2;
        e3 += aldv; e3 = (e3 < 0.f) ? SLOPE * e3 : e3;
        float x0 = __expf(e0), x1 = __expf(e1), x2 = __expf(e2), x3 = __expf(e3);
        dn0 += x0; dn1 += x1; dn2 += x2; dn3 += x3;
        ac0 = fmaf(x0, v0, ac0);
        ac1 = fmaf(x1, v1, ac1);
        ac2 = fmaf(x2, v2, ac2);
        ac3 = fmaf(x3, v3, ac3);
    }
    for (; i < g1; ++i) {
        int s0 = csr[i];
        float e0 = als[s0] + aldv;
        e0 = (e0 < 0.f) ? SLOPE * e0 : e0;
        float x0 = __expf(e0);
        dn0 += x0;
        ac0 = fmaf(x0, (float)h[(size_t)s0 * 16 + lc], ac0);
    }
    float ac = (ac0 + ac1) + (ac2 + ac3);
    float dn = (dn0 + dn1) + (dn2 + dn3);
    ac += __shfl_xor(ac, 16); ac += __shfl_xor(ac, 32);
    dn += __shfl_xor(dn, 16); dn += __shfl_xor(dn, 32);
    if (eg == 0) out[(size_t)nn * 16 + lc] = fmaxf(ac / dn + bias[lc], 0.f);
}

// ---------------- launch ----------------

extern "C" void kernel_launch(void* const* d_in, const int* in_sizes, int n_in,
                              void* d_out, int out_size, void* d_ws, size_t ws_size,
                              hipStream_t stream) {
    const float* x   = (const float*)d_in[0];
    const int*   ei  = (const int*)d_in[1];
    const float* W1  = (const float*)d_in[2];
    const float* as1 = (const float*)d_in[3];
    const float* ad1 = (const float*)d_in[4];
    const float* b1  = (const float*)d_in[5];
    const float* W2  = (const float*)d_in[6];
    const float* as2 = (const float*)d_in[7];
    const float* ad2 = (const float*)d_in[8];
    const float* b2  = (const float*)d_in[9];

    int N = in_sizes[0] / NFEAT;
    int E = in_sizes[1] / 2;
    const int* srcp = ei;
    const int* dstp = ei + E;
    int NBUCK = (N + 255) >> BSH;
    int NBg = (N + 127) / 128;

    char* ws = (char*)d_ws;
    size_t off = 0;
    auto take = [&](size_t bytes) -> char* {
        char* p = ws + off;
        off = (off + bytes + 255) & ~(size_t)255;
        return p;
    };
    int*            row_start = (int*)take((size_t)(N + 1) * 4);
    int*            bcount    = (int*)take(256 * 4);
    int*            cstart    = (int*)take(256 * 4);
    unsigned*       pairs     = (unsigned*)take((size_t)256 << (CAPSH + 2));   // 8 MB
    unsigned short* csr       = (unsigned short*)take((size_t)(E + N) * 2);
    unsigned*       Wt1       = (unsigned*)take((size_t)128 * 64 * 4);
    __fp16*         Aat1      = (__fp16*)take((size_t)16 * 128 * 2);
    unsigned*       W2t       = (unsigned*)take((size_t)16 * 64 * 4);
    unsigned*       h1u       = (unsigned*)take((size_t)N * 64 * 4);   // f16x2
    float*          als1      = (float*)take((size_t)N * 8 * 4);
    float*          ald1      = (float*)take((size_t)N * 8 * 4);
    __fp16*         h2        = (__fp16*)take((size_t)N * 16 * 2);
    float*          als2      = (float*)take((size_t)N * 4);
    float*          ald2      = (float*)take((size_t)N * 4);

    hipMemsetAsync(bcount, 0, 256 * 4, stream);
    int chunk = (E + 255) / 256;
    k_bscatter<<<256, 256, 0, stream>>>(srcp, dstp, E, chunk, bcount, pairs);
    k_scan_prep<<<45, 256, 0, stream>>>(bcount, cstart, row_start, E, N,
                                        W1, as1, ad1, W2, Wt1, Aat1, W2t);
    k_csr_gemm1<<<NBUCK + NBg, 256, 0, stream>>>(pairs, bcount, cstart, row_start, csr,
                                                 x, (const __fp16*)Wt1, Aat1,
                                                 h1u, als1, ald1, N, NBUCK);
    k_agg1<<<(N + 3) / 4, 256, 0, stream>>>(h1u, als1, ald1, b1, row_start, csr,
                                            W2t, as2, ad2, h2, als2, ald2, N);
    k_agg2<<<(N + 3) / 4, 256, 0, stream>>>(h2, als2, ald2, b2, row_start, csr, (float*)d_out, N);
}

// Round 16
// 112.622 us; speedup vs baseline: 1.6376x; 1.0702x over previous
//
#include <hip/hip_runtime.h>

#define NFEAT 128
#define HEADS 8
#define NHID 16
#define SLOPE 0.2f
#define BSH 8            // 256 dst nodes per bucket; requires N <= 65536 (src fits u16)
#define CAPSH 13         // 8192 pairs capacity per bucket (max expected ~4500)

typedef __fp16 f16x8 __attribute__((ext_vector_type(8)));   // MFMA A/B frag (4 VGPRs)
typedef __fp16 f16x2 __attribute__((ext_vector_type(2)));
typedef float  f4v   __attribute__((ext_vector_type(4)));   // MFMA C/D frag

__device__ __forceinline__ unsigned pack2h(float a, float b) {
    union { f16x2 h; unsigned u; } r;
    r.h = __builtin_amdgcn_cvt_pkrtz(a, b);
    return r.u;
}
__device__ __forceinline__ f16x2 as_f16x2(unsigned u) {
    union { unsigned u; f16x2 h; } r; r.u = u; return r.h;
}
__device__ __forceinline__ f16x8 frag_from_f32(const float* p) {
    float4 q0 = *(const float4*)p;
    float4 q1 = *(const float4*)(p + 4);
    union { f16x8 v; f16x2 h[4]; } r;
    r.h[0] = __builtin_amdgcn_cvt_pkrtz(q0.x, q0.y);
    r.h[1] = __builtin_amdgcn_cvt_pkrtz(q0.z, q0.w);
    r.h[2] = __builtin_amdgcn_cvt_pkrtz(q1.x, q1.y);
    r.h[3] = __builtin_amdgcn_cvt_pkrtz(q1.z, q1.w);
    return r.v;
}

// ---------------- CSR build: bscatter into fixed-capacity buckets (no pre-histogram) ----------------

__global__ __launch_bounds__(256) void k_bscatter(const int* __restrict__ src,
                                                  const int* __restrict__ dst,
                                                  int E, int chunk,
                                                  int* __restrict__ bcount,
                                                  unsigned* __restrict__ pairs) {
    __shared__ int cnt[256], base[256];
    int t = threadIdx.x;
    int beg = blockIdx.x * chunk;
    int end = min(beg + chunk, E);
    if (beg >= end) return;
    cnt[t] = 0;
    __syncthreads();
    for (int i = beg + t; i < end; i += 256)
        atomicAdd(&cnt[dst[i] >> BSH], 1);
    __syncthreads();
    int c = cnt[t];
    base[t] = c ? (atomicAdd(&bcount[t], c) + (t << CAPSH)) : 0;
    __syncthreads();
    cnt[t] = 0;
    __syncthreads();
    for (int i = beg + t; i < end; i += 256) {
        int d = dst[i];
        int b = d >> BSH;
        int ofs = atomicAdd(&cnt[b], 1);
        pairs[base[b] + ofs] = (unsigned)src[i] | ((unsigned)(d & 255) << 16);
    }
}

// ---------------- fused: block 0 = bucket-count scan; blocks 1..44 = weight prep ----------------

__global__ __launch_bounds__(256) void k_scan_prep(const int* __restrict__ bcount,
                                                   int* __restrict__ cstart,
                                                   int* __restrict__ row_start,
                                                   int E, int n,
                                                   const float* __restrict__ W1,
                                                   const float* __restrict__ as1,
                                                   const float* __restrict__ ad1,
                                                   const float* __restrict__ W2,
                                                   unsigned* __restrict__ Wt1,
                                                   __fp16* __restrict__ Aat1,
                                                   unsigned* __restrict__ W2t) {
    if (blockIdx.x == 0) {
        __shared__ int sh[256];
        int t = threadIdx.x;
        int nb = (n + 255) >> BSH;
        int v = (t < nb) ? bcount[t] : 0;
        sh[t] = v;
        __syncthreads();
        for (int off = 1; off < 256; off <<= 1) {
            int u = (t >= off) ? sh[t - off] : 0;
            __syncthreads();
            sh[t] += u;
            __syncthreads();
        }
        cstart[t] = sh[t] - v;
        if (t == 0) row_start[n] = E + n;
        return;
    }
    int t = (blockIdx.x - 1) * 256 + threadIdx.x;
    if (t < 8192) {
        int c = t >> 6, m = t & 63;
        int k = 2 * m;
        Wt1[t] = pack2h(W1[k * 128 + c], W1[(k + 1) * 128 + c]);
    } else if (t < 10240) {
        int idx = t - 8192;
        int j = idx >> 7, k = idx & 127;
        float v = 0.f;
        if (j < 8)  { if ((k >> 4) == j)     v = as1[k]; }
        else        { if ((k >> 4) == j - 8) v = ad1[k]; }
        Aat1[idx] = (__fp16)v;
    } else if (t < 11264) {
        int idx = t - 10240;
        int c = idx >> 6, m = idx & 63;
        int k = 2 * m;
        W2t[idx] = pack2h(W2[k * 16 + c], W2[(k + 1) * 16 + c]);
    }
}

// ---------------- fused: blocks [0,nbuck) = per-bucket CSR; blocks [nbuck,..) = layer-1 MFMA GEMM ----------------

__global__ __launch_bounds__(256) void k_csr_gemm1(const unsigned* __restrict__ pairs,
                                                   const int* __restrict__ bcount,
                                                   const int* __restrict__ cstart,
                                                   int* __restrict__ row_start,
                                                   unsigned short* __restrict__ csr,
                                                   const float* __restrict__ xf,
                                                   const __fp16* __restrict__ Wt,
                                                   const __fp16* __restrict__ Aat,
                                                   unsigned* __restrict__ h1u,
                                                   float* __restrict__ als,
                                                   float* __restrict__ ald,
                                                   int n, int nbuck) {
    __shared__ unsigned smem[4][32 * 64];   // 32 KB (gemm repack); csr part aliases 2 KB of it
    if ((int)blockIdx.x < nbuck) {
        int* deg = (int*)&smem[0][0];
        int* sc  = deg + 256;
        int b = blockIdx.x, t = threadIdx.x;
        int d0 = b << BSH;
        int nd = min(256, n - d0);
        deg[t] = (t < nd) ? 1 : 0;   // self loop
        __syncthreads();
        int pbeg = b << CAPSH, pend = pbeg + bcount[b];
        for (int i = pbeg + t; i < pend; i += 256)
            atomicAdd(&deg[(pairs[i] >> 16) & 255], 1);
        __syncthreads();
        int v = deg[t];
        sc[t] = v;
        __syncthreads();
        for (int off = 1; off < 256; off <<= 1) {
            int u = (t >= off) ? sc[t - off] : 0;
            __syncthreads();
            sc[t] += u;
            __syncthreads();
        }
        int excl = sc[t] - v;
        int cbase = cstart[b] + d0;
        if (t < nd) row_start[d0 + t] = cbase + excl;
        __syncthreads();
        deg[t] = excl;                          // reuse as cursor
        __syncthreads();
        if (t < nd) {                           // self loop entry
            int pos = atomicAdd(&deg[t], 1);
            csr[cbase + pos] = (unsigned short)(d0 + t);
        }
        for (int i = pbeg + t; i < pend; i += 256) {
            unsigned p = pairs[i];
            int pos = atomicAdd(&deg[(p >> 16) & 255], 1);
            csr[cbase + pos] = (unsigned short)(p & 0xFFFFu);
        }
        return;
    }
    // ---- gemm1m ----
    int bid = blockIdx.x - nbuck;
    int tid = threadIdx.x;
    int w = tid >> 6, l = tid & 63;
    int l15 = l & 15, lq = l >> 4;
    int wbase = bid * 128 + w * 32;
    f4v acc[2][8] = {};
    int r0 = min(wbase + l15, n - 1);
    int r1 = min(wbase + 16 + l15, n - 1);
#pragma unroll
    for (int kb = 0; kb < 4; ++kb) {
        int ko = kb * 32 + lq * 8;
        f16x8 a0 = frag_from_f32(&xf[(size_t)r0 * 128 + ko]);
        f16x8 a1 = frag_from_f32(&xf[(size_t)r1 * 128 + ko]);
#pragma unroll
        for (int cg = 0; cg < 8; ++cg) {
            f16x8 b = *(const f16x8*)&Wt[(size_t)(cg * 16 + l15) * 128 + ko];
            acc[0][cg] = __builtin_amdgcn_mfma_f32_16x16x32_f16(a0, b, acc[0][cg], 0, 0, 0);
            acc[1][cg] = __builtin_amdgcn_mfma_f32_16x16x32_f16(a1, b, acc[1][cg], 0, 0, 0);
        }
    }
    unsigned* myl = smem[w];
#pragma unroll
    for (int T = 0; T < 2; ++T) {
#pragma unroll
        for (int cg = 0; cg < 8; ++cg) {
#pragma unroll
            for (int j = 0; j < 4; ++j) {
                float v = acc[T][cg][j];
                float vo = __shfl_xor(v, 1);
                if ((l15 & 1) == 0) {
                    int nd = T * 16 + lq * 4 + j;
                    int wd = cg * 8 + (l15 >> 1);
                    int widx = nd * 64 + (((wd >> 2) ^ (nd & 15)) << 2) + (wd & 3);
                    myl[widx] = pack2h(v, vo);
                }
            }
        }
    }
    __syncthreads();
#pragma unroll
    for (int it = 0; it < 8; ++it) {
        int nd = it * 4 + lq;
        int node = wbase + nd;
        uint4 vv = *(const uint4*)&myl[nd * 64 + ((l15 ^ (nd & 15)) << 2)];
        if (node < n) *(uint4*)&h1u[(size_t)node * 64 + l15 * 4] = vv;
    }
#pragma unroll
    for (int T = 0; T < 2; ++T) {
        f4v acca = {};
#pragma unroll
        for (int kb = 0; kb < 4; ++kb) {
            int nd = T * 16 + l15;
            f16x8 ah = *(const f16x8*)&myl[nd * 64 + (((kb * 4 + lq) ^ (nd & 15)) << 2)];
            f16x8 bb = *(const f16x8*)&Aat[l15 * 128 + kb * 32 + lq * 8];
            acca = __builtin_amdgcn_mfma_f32_16x16x32_f16(ah, bb, acca, 0, 0, 0);
        }
#pragma unroll
        for (int j = 0; j < 4; ++j) {
            int node = wbase + T * 16 + lq * 4 + j;
            if (node < n) {
                if (l15 < 8) als[(size_t)node * 8 + l15] = acca[j];
                else         ald[(size_t)node * 8 + (l15 - 8)] = acca[j];
            }
        }
    }
}

// ---------------- Layer 1 aggregation: 2-way channel split, XCD-affine, unroll 4 ----------------
// group g = blockIdx&1 (even/odd XCDs under round-robin); block = 8 nodes x one half-row (128B).
// wave = 2 nodes x 4 edge-slots x 8 lanes x 16B. Instruction cost per edge identical to the
// unsplit kernel (1/4 vmem + 1/4 scalar wave-instr), but each XCD only fetches half of h1.

__global__ __launch_bounds__(256) void k_agg1(const unsigned* __restrict__ hu,
                                              const float* __restrict__ als,
                                              const float* __restrict__ ald,
                                              const float* __restrict__ bias,
                                              const int* __restrict__ row_start,
                                              const unsigned short* __restrict__ csr,
                                              unsigned* __restrict__ out1u, int n) {
    int t = threadIdx.x;
    int w = t >> 6;
    int l = t & 63;
    int lc = l & 7;            // 16B lane within half-row
    int es = (l >> 3) & 3;     // edge slot
    int ns = l >> 5;           // node within wave
    int g = blockIdx.x & 1;    // channel half
    int nn = (blockIdx.x >> 1) * 8 + w * 2 + ns;
    if (nn >= n) return;
    const unsigned* hg = hu + g * 32;          // half-row base offset (u32 words)
    int hd = g * 4 + (lc >> 1);                // head of this lane's 8 channels
    float aldv = ald[(size_t)nn * 8 + hd];
    int beg = row_start[nn], end = row_start[nn + 1];
    int len = end - beg;
    int g0 = beg + ((len * es) >> 2);
    int g1 = beg + ((len * (es + 1)) >> 2);
    float a[8] = {0.f, 0.f, 0.f, 0.f, 0.f, 0.f, 0.f, 0.f};
    float dn = 0.f;
    f16x2 one2; one2[0] = (__fp16)1.f; one2[1] = (__fp16)1.f;
    int i = g0;
    for (; i + 4 <= g1; i += 4) {
        int s0 = csr[i], s1 = csr[i + 1], s2 = csr[i + 2], s3 = csr[i + 3];
        float e0 = als[(size_t)s0 * 8 + hd];
        float e1 = als[(size_t)s1 * 8 + hd];
        float e2 = als[(size_t)s2 * 8 + hd];
        float e3 = als[(size_t)s3 * 8 + hd];
        uint4 v0 = *(const uint4*)&hg[(size_t)s0 * 64 + lc * 4];
        uint4 v1 = *(const uint4*)&hg[(size_t)s1 * 64 + lc * 4];
        uint4 v2 = *(const uint4*)&hg[(size_t)s2 * 64 + lc * 4];
        uint4 v3 = *(const uint4*)&hg[(size_t)s3 * 64 + lc * 4];
        e0 += aldv; e0 = (e0 < 0.f) ? SLOPE * e0 : e0;
        e1 += aldv; e1 = (e1 < 0.f) ? SLOPE * e1 : e1;
        e2 += aldv; e2 = (e2 < 0.f) ? SLOPE * e2 : e2;
        e3 += aldv; e3 = (e3 < 0.f) ? SLOPE * e3 : e3;
        f16x2 xa = __builtin_amdgcn_cvt_pkrtz(__expf(e0), __expf(e1));
        f16x2 xb = __builtin_amdgcn_cvt_pkrtz(__expf(e2), __expf(e3));
        dn = __builtin_amdgcn_fdot2(xa, one2, dn, false);
        dn = __builtin_amdgcn_fdot2(xb, one2, dn, false);
        unsigned V0[4] = {v0.x, v0.y, v0.z, v0.w};
        unsigned V1[4] = {v1.x, v1.y, v1.z, v1.w};
        unsigned V2[4] = {v2.x, v2.y, v2.z, v2.w};
        unsigned V3[4] = {v3.x, v3.y, v3.z, v3.w};
#pragma unroll
        for (int j = 0; j < 4; ++j) {
            unsigned lo01 = __builtin_amdgcn_perm(V1[j], V0[j], 0x05040100u);
            unsigned hi01 = __builtin_amdgcn_perm(V1[j], V0[j], 0x07060302u);
            unsigned lo23 = __builtin_amdgcn_perm(V3[j], V2[j], 0x05040100u);
            unsigned hi23 = __builtin_amdgcn_perm(V3[j], V2[j], 0x07060302u);
            a[2 * j]     = __builtin_amdgcn_fdot2(xa, as_f16x2(lo01), a[2 * j], false);
            a[2 * j + 1] = __builtin_amdgcn_fdot2(xa, as_f16x2(hi01), a[2 * j + 1], false);
            a[2 * j]     = __builtin_amdgcn_fdot2(xb, as_f16x2(lo23), a[2 * j], false);
            a[2 * j + 1] = __builtin_amdgcn_fdot2(xb, as_f16x2(hi23), a[2 * j + 1], false);
        }
    }
    for (; i + 2 <= g1; i += 2) {
        int s0 = csr[i];
        int s1 = csr[i + 1];
        float e0 = als[(size_t)s0 * 8 + hd];
        float e1 = als[(size_t)s1 * 8 + hd];
        uint4 v0 = *(const uint4*)&hg[(size_t)s0 * 64 + lc * 4];
        uint4 v1 = *(const uint4*)&hg[(size_t)s1 * 64 + lc * 4];
        e0 += aldv; e0 = (e0 < 0.f) ? SLOPE * e0 : e0;
        e1 += aldv; e1 = (e1 < 0.f) ? SLOPE * e1 : e1;
        f16x2 xx = __builtin_amdgcn_cvt_pkrtz(__expf(e0), __expf(e1));
        dn = __builtin_amdgcn_fdot2(xx, one2, dn, false);
        unsigned V0[4] = {v0.x, v0.y, v0.z, v0.w};
        unsigned V1[4] = {v1.x, v1.y, v1.z, v1.w};
#pragma unroll
        for (int j = 0; j < 4; ++j) {
            unsigned lo = __builtin_amdgcn_perm(V1[j], V0[j], 0x05040100u);
            unsigned hi = __builtin_amdgcn_perm(V1[j], V0[j], 0x07060302u);
            a[2 * j]     = __builtin_amdgcn_fdot2(xx, as_f16x2(lo), a[2 * j], false);
            a[2 * j + 1] = __builtin_amdgcn_fdot2(xx, as_f16x2(hi), a[2 * j + 1], false);
        }
    }
    if (i < g1) {
        int s0 = csr[i];
        float e0 = als[(size_t)s0 * 8 + hd] + aldv;
        uint4 v0 = *(const uint4*)&hg[(size_t)s0 * 64 + lc * 4];
        e0 = (e0 < 0.f) ? SLOPE * e0 : e0;
        float x0 = __expf(e0);
        dn += x0;
        unsigned V0[4] = {v0.x, v0.y, v0.z, v0.w};
#pragma unroll
        for (int j = 0; j < 4; ++j) {
            f16x2 p = as_f16x2(V0[j]);
            a[2 * j]     = fmaf(x0, (float)p[0], a[2 * j]);
            a[2 * j + 1] = fmaf(x0, (float)p[1], a[2 * j + 1]);
        }
    }
    // reduce over 4 edge-slots (strides 8,16 stay within the node's 32 lanes)
#pragma unroll
    for (int j = 0; j < 8; ++j) {
        a[j] += __shfl_xor(a[j], 8);
        a[j] += __shfl_xor(a[j], 16);
    }
    dn += __shfl_xor(dn, 8);
    dn += __shfl_xor(dn, 16);
    if (es == 0) {
        float inv = 1.f / dn;
        int ch = g * 64 + lc * 8;
        float4 b0 = *(const float4*)&bias[ch];
        float4 b1 = *(const float4*)&bias[ch + 4];
        uint4 o;
        o.x = pack2h(fmaxf(a[0] * inv + b0.x, 0.f), fmaxf(a[1] * inv + b0.y, 0.f));
        o.y = pack2h(fmaxf(a[2] * inv + b0.z, 0.f), fmaxf(a[3] * inv + b0.w, 0.f));
        o.z = pack2h(fmaxf(a[4] * inv + b1.x, 0.f), fmaxf(a[5] * inv + b1.y, 0.f));
        o.w = pack2h(fmaxf(a[6] * inv + b1.z, 0.f), fmaxf(a[7] * inv + b1.w, 0.f));
        *(uint4*)&out1u[(size_t)nn * 64 + g * 32 + lc * 4] = o;
    }
}

// ---------------- Layer 2 GEMM via MFMA (f16) ----------------

__global__ __launch_bounds__(256) void k_gemm2m(const __fp16* __restrict__ o1,
                                                const __fp16* __restrict__ W2t,
                                                const float* __restrict__ as2,
                                                const float* __restrict__ ad2,
                                                __fp16* __restrict__ h2,
                                                float* __restrict__ als,
                                                float* __restrict__ ald, int n) {
    int tid = threadIdx.x;
    int w = tid >> 6, l = tid & 63;
    int l15 = l & 15, lq = l >> 4;
    int wbase = blockIdx.x * 128 + w * 32;
    f4v acc[2] = {};
    int r0 = min(wbase + l15, n - 1);
    int r1 = min(wbase + 16 + l15, n - 1);
#pragma unroll
    for (int kb = 0; kb < 4; ++kb) {
        int ko = kb * 32 + lq * 8;
        f16x8 a0 = *(const f16x8*)&o1[(size_t)r0 * 128 + ko];
        f16x8 a1 = *(const f16x8*)&o1[(size_t)r1 * 128 + ko];
        f16x8 b  = *(const f16x8*)&W2t[(size_t)l15 * 128 + ko];
        acc[0] = __builtin_amdgcn_mfma_f32_16x16x32_f16(a0, b, acc[0], 0, 0, 0);
        acc[1] = __builtin_amdgcn_mfma_f32_16x16x32_f16(a1, b, acc[1], 0, 0, 0);
    }
    float asv = as2[l15], adv = ad2[l15];
#pragma unroll
    for (int T = 0; T < 2; ++T) {
#pragma unroll
        for (int j = 0; j < 4; ++j) {
            int node = wbase + T * 16 + lq * 4 + j;
            float hv = acc[T][j];
            float ps = hv * asv, pd = hv * adv;
            ps += __shfl_xor(ps, 1); ps += __shfl_xor(ps, 2);
            ps += __shfl_xor(ps, 4); ps += __shfl_xor(ps, 8);
            pd += __shfl_xor(pd, 1); pd += __shfl_xor(pd, 2);
            pd += __shfl_xor(pd, 4); pd += __shfl_xor(pd, 8);
            if (node < n) {
                h2[(size_t)node * 16 + l15] = (__fp16)hv;
                if (l15 == 0) { als[node] = ps; ald[node] = pd; }
            }
        }
    }
}

// ---------------- Layer 2 aggregation (unroll 4) ----------------

__global__ __launch_bounds__(256) void k_agg2(const __fp16* __restrict__ h,
                                              const float* __restrict__ als,
                                              const float* __restrict__ ald,
                                              const float* __restrict__ bias,
                                              const int* __restrict__ row_start,
                                              const unsigned short* __restrict__ csr,
                                              float* __restrict__ out, int n) {
    int t = threadIdx.x;
    int l = t & 63;
    int lc = l & 15, eg = l >> 4;
    int nn = blockIdx.x * 4 + (t >> 6);
    if (nn >= n) return;
    int beg = row_start[nn], end = row_start[nn + 1];
    int len = end - beg;
    int g0 = beg + ((len * eg) >> 2);
    int g1 = beg + ((len * (eg + 1)) >> 2);
    float aldv = ald[nn];
    float ac0 = 0.f, ac1 = 0.f, ac2 = 0.f, ac3 = 0.f;
    float dn0 = 0.f, dn1 = 0.f, dn2 = 0.f, dn3 = 0.f;
    int i = g0;
    for (; i + 4 <= g1; i += 4) {
        int s0 = csr[i], s1 = csr[i + 1], s2 = csr[i + 2], s3 = csr[i + 3];
        float e0 = als[s0], e1 = als[s1], e2 = als[s2], e3 = als[s3];
        float v0 = (float)h[(size_t)s0 * 16 + lc];
        float v1 = (float)h[(size_t)s1 * 16 + lc];
        float v2 = (float)h[(size_t)s2 * 16 + lc];
        float v3 = (float)h[(size_t)s3 * 16 + lc];
        e0 += aldv; e0 = (e0 < 0.f) ? SLOPE * e0 : e0;
        e1 += aldv; e1 = (e1 < 0.f) ? SLOPE * e1 : e1;
        e2 += aldv; e2 = (e2 < 0.f) ? SLOPE * e2 : e2;
        e3 += aldv; e3 = (e3 < 0.f) ? SLOPE * e3 : e3;
        float x0 = __expf(e0), x1 = __expf(e1), x2 = __expf(e2), x3 = __expf(e3);
        dn0 += x0; dn1 += x1; dn2 += x2; dn3 += x3;
        ac0 = fmaf(x0, v0, ac0);
        ac1 = fmaf(x1, v1, ac1);
        ac2 = fmaf(x2, v2, ac2);
        ac3 = fmaf(x3, v3, ac3);
    }
    for (; i < g1; ++i) {
        int s0 = csr[i];
        float e0 = als[s0] + aldv;
        e0 = (e0 < 0.f) ? SLOPE * e0 : e0;
        float x0 = __expf(e0);
        dn0 += x0;
        ac0 = fmaf(x0, (float)h[(size_t)s0 * 16 + lc], ac0);
    }
    float ac = (ac0 + ac1) + (ac2 + ac3);
    float dn = (dn0 + dn1) + (dn2 + dn3);
    ac += __shfl_xor(ac, 16); ac += __shfl_xor(ac, 32);
    dn += __shfl_xor(dn, 16); dn += __shfl_xor(dn, 32);
    if (eg == 0) out[(size_t)nn * 16 + lc] = fmaxf(ac / dn + bias[lc], 0.f);
}

// ---------------- launch ----------------

extern "C" void kernel_launch(void* const* d_in, const int* in_sizes, int n_in,
                              void* d_out, int out_size, void* d_ws, size_t ws_size,
                              hipStream_t stream) {
    const float* x   = (const float*)d_in[0];
    const int*   ei  = (const int*)d_in[1];
    const float* W1  = (const float*)d_in[2];
    const float* as1 = (const float*)d_in[3];
    const float* ad1 = (const float*)d_in[4];
    const float* b1  = (const float*)d_in[5];
    const float* W2  = (const float*)d_in[6];
    const float* as2 = (const float*)d_in[7];
    const float* ad2 = (const float*)d_in[8];
    const float* b2  = (const float*)d_in[9];

    int N = in_sizes[0] / NFEAT;
    int E = in_sizes[1] / 2;
    const int* srcp = ei;
    const int* dstp = ei + E;
    int NBUCK = (N + 255) >> BSH;
    int NBg = (N + 127) / 128;

    char* ws = (char*)d_ws;
    size_t off = 0;
    auto take = [&](size_t bytes) -> char* {
        char* p = ws + off;
        off = (off + bytes + 255) & ~(size_t)255;
        return p;
    };
    int*            row_start = (int*)take((size_t)(N + 1) * 4);
    int*            bcount    = (int*)take(256 * 4);
    int*            cstart    = (int*)take(256 * 4);
    unsigned*       pairs     = (unsigned*)take((size_t)256 << (CAPSH + 2));   // 8 MB
    unsigned short* csr       = (unsigned short*)take((size_t)(E + N) * 2);
    unsigned*       Wt1       = (unsigned*)take((size_t)128 * 64 * 4);
    __fp16*         Aat1      = (__fp16*)take((size_t)16 * 128 * 2);
    unsigned*       W2t       = (unsigned*)take((size_t)16 * 64 * 4);
    unsigned*       h1u       = (unsigned*)take((size_t)N * 64 * 4);   // f16x2
    float*          als1      = (float*)take((size_t)N * 8 * 4);
    float*          ald1      = (float*)take((size_t)N * 8 * 4);
    unsigned*       out1u     = (unsigned*)take((size_t)N * 64 * 4);   // f16x2
    __fp16*         h2        = (__fp16*)take((size_t)N * 16 * 2);
    float*          als2      = (float*)take((size_t)N * 4);
    float*          ald2      = (float*)take((size_t)N * 4);

    hipMemsetAsync(bcount, 0, 256 * 4, stream);
    int chunk = (E + 255) / 256;
    k_bscatter<<<256, 256, 0, stream>>>(srcp, dstp, E, chunk, bcount, pairs);
    k_scan_prep<<<45, 256, 0, stream>>>(bcount, cstart, row_start, E, N,
                                        W1, as1, ad1, W2, Wt1, Aat1, W2t);
    k_csr_gemm1<<<NBUCK + NBg, 256, 0, stream>>>(pairs, bcount, cstart, row_start, csr,
                                                 x, (const __fp16*)Wt1, Aat1,
                                                 h1u, als1, ald1, N, NBUCK);
    int nb1 = ((N + 7) / 8) * 2;   // 8 nodes per block x 2 channel halves
    k_agg1<<<nb1, 256, 0, stream>>>(h1u, als1, ald1, b1, row_start, csr, out1u, N);
    k_gemm2m<<<NBg, 256, 0, stream>>>((const __fp16*)out1u, (const __fp16*)W2t,
                                      as2, ad2, h2, als2, ald2, N);
    k_agg2<<<(N + 3) / 4, 256, 0, stream>>>(h2, als2, ald2, b2, row_start, csr, (float*)d_out, N);
}